// Round 12
// baseline (21802.844 us; speedup 1.0000x reference)
//
#include <hip/hip_runtime.h>

#define T_   2048
#define NWG  32

typedef float  float4v __attribute__((ext_vector_type(4)));
typedef float  float2v __attribute__((ext_vector_type(2)));
typedef short  short8v __attribute__((ext_vector_type(8)));
typedef short  short4v __attribute__((ext_vector_type(4)));
typedef unsigned uint4v __attribute__((ext_vector_type(4)));
typedef unsigned uint2v __attribute__((ext_vector_type(2)));
typedef unsigned short ushort_t;

__device__ __forceinline__ ushort_t f2bf(float f) {
  union { float f; unsigned u; } v; v.f = f;
  unsigned r = (v.u + 0x7FFFu + ((v.u >> 16) & 1u)) >> 16;  // RTN
  return (ushort_t)r;
}
__device__ __forceinline__ float bf2f(short s) {
  union { unsigned u; float f; } v; v.u = ((unsigned)(unsigned short)s) << 16;
  return v.f;
}
__device__ __forceinline__ float sigm(float x) {
  x = fmaxf(x, -30.f);
  return __fdividef(1.f, 1.f + __expf(-x));
}
__device__ __forceinline__ float tanh_(float x) {
  x = fminf(fmaxf(x, -15.f), 15.f);
  float e = __expf(2.f * x);
  return (e - 1.f) * __fdividef(1.f, e + 1.f);
}

// Coherence-point ops (bypass L1+L2, no cache-wide invalidate). Inline-asm
// vmem is NOT tracked by compiler waitcnt — wait manually + sched_barrier.
__device__ __forceinline__ uint4v ld_tag16(const unsigned* p) {
  uint4v r;
  asm volatile("global_load_dwordx4 %0, %1, off sc0 sc1" : "=v"(r) : "v"(p));
  return r;
}
__device__ __forceinline__ void st_tag8(unsigned* p, uint2v v) {
  asm volatile("global_store_dwordx2 %0, %1, off sc0 sc1" :: "v"(p), "v"(v) : "memory");
}
__device__ __forceinline__ short8v ld_coh16(const ushort_t* p) {
  short8v r;
  asm volatile("global_load_dwordx4 %0, %1, off sc0 sc1" : "=v"(r) : "v"(p));
  return r;
}
// pack two tagged dword-quads (value in hi16) into one bf16x8 fragment
__device__ __forceinline__ short8v pack_tagged(uint4v a, uint4v b) {
  uint4v pk;
  pk[0] = __builtin_amdgcn_perm(a[1], a[0], 0x07060302u);
  pk[1] = __builtin_amdgcn_perm(a[3], a[2], 0x07060302u);
  pk[2] = __builtin_amdgcn_perm(b[1], b[0], 0x07060302u);
  pk[3] = __builtin_amdgcn_perm(b[3], b[2], 0x07060302u);
  return __builtin_bit_cast(short8v, pk);
}

// W1[n,k] = sum_j W_hh[n,j] * W_hs[j,k]   (fold: h2 @ W_hh^T == h_new @ W1^T)
__global__ void k_prep_w1(const float* __restrict__ Whh, const float* __restrict__ Whs,
                          ushort_t* __restrict__ w1) {
  int idx = blockIdx.x * 256 + threadIdx.x;
  if (idx >= 2048 * 512) return;
  int n = idx >> 9, k = idx & 511;
  const float* whr = Whh + (size_t)n * 512;
  const float* wsk = Whs + k;
  float s = 0.f;
  #pragma unroll 8
  for (int j = 0; j < 512; ++j) s += whr[j] * wsk[(size_t)j * 512];
  w1[idx] = f2bf(s);
}

__global__ void k_prep_misc(const float* __restrict__ Wih, const float* __restrict__ Wcs,
                            const float* __restrict__ Whs, const float* __restrict__ bih,
                            const float* __restrict__ bhh,
                            ushort_t* __restrict__ wih_bf, ushort_t* __restrict__ wcs_bf,
                            ushort_t* __restrict__ whs_bf, float* __restrict__ bias,
                            unsigned* __restrict__ HT, unsigned* __restrict__ CT,
                            int* __restrict__ flags) {
  // HT/CT: 2-slot tagged rings (32768 dwords each) — zero BOTH slots every
  // launch so stale tags from a previous replay can never alias.
  const int total = 1048576 + 262144 + 262144 + 2048 + 32768 + 32768 + 512;
  for (int i = blockIdx.x * blockDim.x + threadIdx.x; i < total; i += gridDim.x * blockDim.x) {
    int r = i;
    if (r < 1048576) { wih_bf[r] = f2bf(Wih[r]); continue; }
    r -= 1048576;
    if (r < 262144)  { wcs_bf[r] = f2bf(Wcs[r]); continue; }
    r -= 262144;
    if (r < 262144)  { whs_bf[r] = f2bf(Whs[r]); continue; }
    r -= 262144;
    if (r < 2048)    { bias[r] = bih[r] + bhh[r]; continue; }
    r -= 2048;
    if (r < 32768)   { HT[r] = 0u; continue; }
    r -= 32768;
    if (r < 32768)   { CT[r] = 0u; continue; }
    r -= 32768;
    flags[r] = 0;   // fallback-path flags
  }
}

// G[t][fb][gate][col][batch] = (X_t @ Wih^T) in MFMA C-fragment order, bf16.
__global__ __launch_bounds__(256) void k_gemm_g(
    const float* __restrict__ X, const ushort_t* __restrict__ wih,
    ushort_t* __restrict__ G) {
  const int bid = blockIdx.x;
  const int fb  = bid & 31;
  const int tg  = bid >> 5;
  const int wid = threadIdx.x >> 6;
  const int lane = threadIdx.x & 63;
  const int t   = tg * 4 + wid;
  const int ar  = lane & 15;
  const int ko  = (lane >> 4) << 3;

  float4v acc[2][4];
  #pragma unroll
  for (int mh = 0; mh < 2; ++mh)
    #pragma unroll
    for (int cg = 0; cg < 4; ++cg)
      acc[mh][cg] = float4v{0.f, 0.f, 0.f, 0.f};

  #pragma unroll 4
  for (int kk = 0; kk < 16; ++kk) {
    short8v a[2];
    #pragma unroll
    for (int mh = 0; mh < 2; ++mh) {
      const float* p = X + (size_t)(mh * 16 + ar) * (T_ * 512) + (size_t)t * 512 + kk * 32 + ko;
      float4v xa = *(const float4v*)(p);
      float4v xb = *(const float4v*)(p + 4);
      uint4v ua = __builtin_bit_cast(uint4v, xa);
      uint4v ub = __builtin_bit_cast(uint4v, xb);
      uint4v pk;
      pk[0] = __builtin_amdgcn_perm(ua[1], ua[0], 0x07060302u);
      pk[1] = __builtin_amdgcn_perm(ua[3], ua[2], 0x07060302u);
      pk[2] = __builtin_amdgcn_perm(ub[1], ub[0], 0x07060302u);
      pk[3] = __builtin_amdgcn_perm(ub[3], ub[2], 0x07060302u);
      a[mh] = __builtin_bit_cast(short8v, pk);
    }
    #pragma unroll
    for (int cg = 0; cg < 4; ++cg) {
      short8v b = *(const short8v*)(wih + ((size_t)(cg * 512 + fb * 16 + ar)) * 512 + kk * 32 + ko);
      acc[0][cg] = __builtin_amdgcn_mfma_f32_16x16x32_bf16(a[0], b, acc[0][cg], 0, 0, 0);
      acc[1][cg] = __builtin_amdgcn_mfma_f32_16x16x32_bf16(a[1], b, acc[1][cg], 0, 0, 0);
    }
  }

  const size_t base = ((size_t)t * 32 + fb) * 2048;
  #pragma unroll
  for (int mh = 0; mh < 2; ++mh)
    #pragma unroll
    for (int cg = 0; cg < 4; ++cg) {
      short4v s;
      #pragma unroll
      for (int r = 0; r < 4; ++r) s[r] = (short)f2bf(acc[mh][cg][r]);
      *(short4v*)(G + base + cg * 512 + ar * 32 + mh * 16 + ((lane >> 4) << 2)) = s;
    }
}

// ===== main: G-precompute + SEQUENCE-TAGGED state =====
// State dword = (bf16 value)<<16 | tag; producer at step t stores tag t+1
// into slot t&1 with NO drain and NO flag. Consumer at step t sentinel-polls
// then tag-checks slot (t-1)&1 expecting tag t — detection IS the load.
// Ring-2 safe: each WG's read-before-store orders overwrites (see r9 audit).
__global__ __launch_bounds__(256, 1) void k_lstm_tag2(
    const float* __restrict__ X,
    const ushort_t* __restrict__ w1,
    const ushort_t* __restrict__ wcs, const ushort_t* __restrict__ whs,
    const float* __restrict__ bias, const ushort_t* __restrict__ G,
    unsigned* __restrict__ HT, unsigned* __restrict__ CT,
    float* __restrict__ out)
{
  const int fb   = blockIdx.x;
  const int tid  = threadIdx.x;
  const int wid  = tid >> 6;
  const int lane = tid & 63;
  const int mh   = wid & 1;
  const int ar   = lane & 15;
  const int ko   = (lane >> 4) << 3;

  __shared__ float s_tiles[2][12][16][20];   // double-buffered by t&1

  const int eb  = tid >> 3;
  const int ejp = (tid & 7) * 2;
  const int emh = eb >> 4, ebr = eb & 15;
  float bI[2], bF[2], bG[2], bO[2];
  #pragma unroll
  for (int u = 0; u < 2; ++u) {
    bI[u] = bias[0 * 512 + fb * 16 + ejp + u];
    bF[u] = bias[1 * 512 + fb * 16 + ejp + u];
    bG[u] = bias[2 * 512 + fb * 16 + ejp + u];
    bO[u] = bias[3 * 512 + fb * 16 + ejp + u];
  }

  const int gtype0 = wid >> 1;
  const int gtype1 = 2 + (wid >> 1);

  // state-pass B fragments: load ONCE into registers (AGPR-backed)
  short8v bw0[16], bw1[16], bw2[16];
  {
    const ushort_t* p0 = w1 + ((size_t)(gtype0 * 512 + fb * 16 + ar)) * 512 + ko;
    const ushort_t* p1 = w1 + ((size_t)(gtype1 * 512 + fb * 16 + ar)) * 512 + ko;
    const ushort_t* p2 = ((wid < 2) ? wcs : whs) + ((size_t)(fb * 16 + ar)) * 512 + ko;
    #pragma unroll
    for (int kk = 0; kk < 16; ++kk) {
      bw0[kk] = *(const short8v*)(p0 + (size_t)kk * 32);
      bw1[kk] = *(const short8v*)(p1 + (size_t)kk * 32);
      bw2[kk] = *(const short8v*)(p2 + (size_t)kk * 32);
    }
  }

  const int arow_x = mh * 16 + ar;
  const int t0 = wid, t1 = wid + 4, t2 = wid + 8;
  const int glo = ((lane >> 4) << 2) + mh * 16 + ar * 32;

  short4v gp0, gp1;
  {   // prologue G prefetch for t=0
    const ushort_t* gb = G + (size_t)fb * 2048 + glo;
    gp0 = *(const short4v*)(gb + gtype0 * 512);
    gp1 = *(const short4v*)(gb + gtype1 * 512);
  }

  bool dead = false;   // sticky escape: any protocol bug -> fast FAIL, not hang

  for (int t = 0; t <= T_; ++t) {
    // ---- prefetch output-pass X for step t-2 ----
    float2v xo2 = {0.f, 0.f};
    if (t >= 2)
      xo2 = *(const float2v*)&X[(size_t)eb * (T_ * 512) + (size_t)(t - 2) * 512 + fb * 16 + ejp];

    const int rs = (t + 1) & 1;          // read slot = (t-1)&1
    const unsigned tg = (unsigned)t;
    const unsigned* hb = HT + rs * 16384 + arow_x * 512 + ko;
    const unsigned* cb = CT + rs * 16384 + arow_x * 512 + ko;

    // ---- sentinel pre-poll: 1 dword per producer-WG per array ----
    if (t > 0) {
      const unsigned* sh = HT + rs * 16384 + 31 * 512 + (lane & 31) * 16 + 14;
      const unsigned* sc = CT + rs * 16384 + 31 * 512 + (lane & 31) * 16 + 14;
      int tries = 0;
      while (true) {
        unsigned v0, v1;
        asm volatile("global_load_dword %0, %2, off sc0 sc1\n\t"
                     "global_load_dword %1, %3, off sc0 sc1\n\t"
                     "s_waitcnt vmcnt(0)"
                     : "=v"(v0), "=v"(v1) : "v"(sh), "v"(sc) : "memory");
        unsigned bad = ((v0 ^ tg) | (v1 ^ tg)) & 0xFFFFu;
        if (__all(bad == 0)) break;
        if (dead || ++tries > (1 << 17)) { dead = true; break; }
      }
      __builtin_amdgcn_sched_barrier(0);
    }

    // ---- half A (kk 0..7): tagged load + check + retry ----
    uint4v sA[16], sCA[16];
    {
      int triesA = 0;
      while (true) {
        #pragma unroll
        for (int kk = 0; kk < 8; ++kk) {
          sA[2 * kk]     = ld_tag16(hb + kk * 32);
          sA[2 * kk + 1] = ld_tag16(hb + kk * 32 + 4);
        }
        if (wid < 2) {
          #pragma unroll
          for (int kk = 0; kk < 8; ++kk) {
            sCA[2 * kk]     = ld_tag16(cb + kk * 32);
            sCA[2 * kk + 1] = ld_tag16(cb + kk * 32 + 4);
          }
        }
        asm volatile("s_waitcnt vmcnt(0)" ::: "memory");
        __builtin_amdgcn_sched_barrier(0);
        unsigned bad = 0;
        #pragma unroll
        for (int i = 0; i < 16; ++i) bad |= (sA[i][0] ^ tg) | (sA[i][2] ^ tg);
        if (wid < 2) {
          #pragma unroll
          for (int i = 0; i < 16; ++i) bad |= (sCA[i][0] ^ tg) | (sCA[i][2] ^ tg);
        }
        bad &= 0xFFFFu;
        if (__all(bad == 0)) break;
        if (dead || ++triesA > 4096) { dead = true; break; }
      }
      __builtin_amdgcn_sched_barrier(0);
    }

    // ---- repack A (frees sA/sCA), then ISSUE half B into the same staging ----
    short8v ah[8], ac[8];
    #pragma unroll
    for (int kk = 0; kk < 8; ++kk) ah[kk] = pack_tagged(sA[2 * kk], sA[2 * kk + 1]);
    if (wid < 2) {
      #pragma unroll
      for (int kk = 0; kk < 8; ++kk) ac[kk] = pack_tagged(sCA[2 * kk], sCA[2 * kk + 1]);
    }
    #pragma unroll
    for (int kk = 0; kk < 8; ++kk) {
      sA[2 * kk]     = ld_tag16(hb + (8 + kk) * 32);
      sA[2 * kk + 1] = ld_tag16(hb + (8 + kk) * 32 + 4);
    }
    if (wid < 2) {
      #pragma unroll
      for (int kk = 0; kk < 8; ++kk) {
        sCA[2 * kk]     = ld_tag16(cb + (8 + kk) * 32);
        sCA[2 * kk + 1] = ld_tag16(cb + (8 + kk) * 32 + 4);
      }
    }
    __builtin_amdgcn_sched_barrier(0);

    // ---- work in half-B's flight: acc init from G + out-pass(t-2) + MFMA A ----
    float4v acc0, acc1, acc2;
    #pragma unroll
    for (int r = 0; r < 4; ++r) {
      acc0[r] = bf2f(gp0[r]);
      acc1[r] = bf2f(gp1[r]);
      acc2[r] = 0.f;
    }
    float ov2[2];
    if (t >= 2) {
      const int p = (t - 1) & 1;
      #pragma unroll
      for (int u = 0; u < 2; ++u) {
        int j = ejp + u;
        float c2p = s_tiles[p][8 + emh][ebr][j];
        float h2p = s_tiles[p][10 + emh][ebr][j];
        float att = tanh_(h2p + c2p);
        float xo  = (u ? xo2[1] : xo2[0]);
        float o1  = tanh_(att + xo);
        ov2[u] = xo + tanh_(o1);
      }
    }
    #pragma unroll
    for (int kk = 0; kk < 8; ++kk) {
      acc0 = __builtin_amdgcn_mfma_f32_16x16x32_bf16(ah[kk], bw0[kk], acc0, 0, 0, 0);
      acc1 = __builtin_amdgcn_mfma_f32_16x16x32_bf16(ah[kk], bw1[kk], acc1, 0, 0, 0);
      short8v a2 = (wid < 2) ? ac[kk] : ah[kk];
      acc2 = __builtin_amdgcn_mfma_f32_16x16x32_bf16(a2, bw2[kk], acc2, 0, 0, 0);
    }
    __builtin_amdgcn_sched_barrier(0);

    // ---- half B: wait + check + (rare) retry ----
    {
      int triesB = 0;
      while (true) {
        asm volatile("s_waitcnt vmcnt(0)" ::: "memory");
        __builtin_amdgcn_sched_barrier(0);
        unsigned bad = 0;
        #pragma unroll
        for (int i = 0; i < 16; ++i) bad |= (sA[i][0] ^ tg) | (sA[i][2] ^ tg);
        if (wid < 2) {
          #pragma unroll
          for (int i = 0; i < 16; ++i) bad |= (sCA[i][0] ^ tg) | (sCA[i][2] ^ tg);
        }
        bad &= 0xFFFFu;
        if (__all(bad == 0)) break;
        if (dead || ++triesB > 4096) { dead = true; break; }
        #pragma unroll
        for (int kk = 0; kk < 8; ++kk) {
          sA[2 * kk]     = ld_tag16(hb + (8 + kk) * 32);
          sA[2 * kk + 1] = ld_tag16(hb + (8 + kk) * 32 + 4);
        }
        if (wid < 2) {
          #pragma unroll
          for (int kk = 0; kk < 8; ++kk) {
            sCA[2 * kk]     = ld_tag16(cb + (8 + kk) * 32);
            sCA[2 * kk + 1] = ld_tag16(cb + (8 + kk) * 32 + 4);
          }
        }
      }
      __builtin_amdgcn_sched_barrier(0);
    }

    // ---- repack B + MFMA B ----
    {
      short8v bh[8], bc[8];
      #pragma unroll
      for (int kk = 0; kk < 8; ++kk) bh[kk] = pack_tagged(sA[2 * kk], sA[2 * kk + 1]);
      if (wid < 2) {
        #pragma unroll
        for (int kk = 0; kk < 8; ++kk) bc[kk] = pack_tagged(sCA[2 * kk], sCA[2 * kk + 1]);
      }
      #pragma unroll
      for (int kk = 0; kk < 8; ++kk) {
        acc0 = __builtin_amdgcn_mfma_f32_16x16x32_bf16(bh[kk], bw0[8 + kk], acc0, 0, 0, 0);
        acc1 = __builtin_amdgcn_mfma_f32_16x16x32_bf16(bh[kk], bw1[8 + kk], acc1, 0, 0, 0);
        short8v a2 = (wid < 2) ? bc[kk] : bh[kk];
        acc2 = __builtin_amdgcn_mfma_f32_16x16x32_bf16(a2, bw2[8 + kk], acc2, 0, 0, 0);
      }
    }

    // ---- C tiles -> LDS (buffer t&1) ----
    const int pb = t & 1;
    {
      const int rb = (lane >> 4) << 2, cc = lane & 15;
      #pragma unroll
      for (int r = 0; r < 4; ++r) {
        s_tiles[pb][t0][rb + r][cc] = acc0[r];
        s_tiles[pb][t1][rb + r][cc] = acc1[r];
        s_tiles[pb][t2][rb + r][cc] = acc2[r];
      }
    }
    __syncthreads();   // the ONE barrier per step

    // ---- elementwise cell update + TAGGED store (no drain, no flag!) ----
    if (t < T_) {
      const unsigned tg1 = (unsigned)(t + 1) & 0xFFFFu;
      uint2v hv, cv;
      #pragma unroll
      for (int u = 0; u < 2; ++u) {
        int j = ejp + u;
        float iv  = s_tiles[pb][0 + emh][ebr][j] + bI[u];
        float fv  = s_tiles[pb][2 + emh][ebr][j] + bF[u];
        float gv  = s_tiles[pb][4 + emh][ebr][j] + bG[u];
        float ov  = s_tiles[pb][6 + emh][ebr][j] + bO[u];
        float c2p = s_tiles[pb][8 + emh][ebr][j];
        float cnv = sigm(fv) * c2p + sigm(iv) * tanh_(gv);
        float hnv = sigm(ov) * tanh_(cnv);
        hv[u] = (((unsigned)f2bf(hnv)) << 16) | tg1;
        cv[u] = (((unsigned)f2bf(cnv)) << 16) | tg1;
      }
      const int uso = (t & 1) * 16384 + eb * 512 + fb * 16 + ejp;
      st_tag8(HT + uso, hv);
      st_tag8(CT + uso, cv);
    }

    // ---- deferred out store for step t-2 ----
    if (t >= 2) {
      float2v o2; o2[0] = ov2[0]; o2[1] = ov2[1];
      *(float2v*)&out[(size_t)eb * (T_ * 512) + (size_t)(t - 2) * 512 + fb * 16 + ejp] = o2;
    }

    // ---- prefetch next step's G fragment ----
    if (t + 1 < T_) {
      const ushort_t* gb = G + ((size_t)((t + 1) * 32 + fb)) * 2048 + glo;
      gp0 = *(const short4v*)(gb + gtype0 * 512);
      gp1 = *(const short4v*)(gb + gtype1 * 512);
    }
  }

  // ---- epilogue: out[T-1] from buffer T&1 ----
  {
    const int p = T_ & 1;
    float2v xo2 = *(const float2v*)&X[(size_t)eb * (T_ * 512) + (size_t)(T_ - 1) * 512 + fb * 16 + ejp];
    float ov2[2];
    #pragma unroll
    for (int u = 0; u < 2; ++u) {
      int j = ejp + u;
      float c2p = s_tiles[p][8 + emh][ebr][j];
      float h2p = s_tiles[p][10 + emh][ebr][j];
      float att = tanh_(h2p + c2p);
      float xo  = (u ? xo2[1] : xo2[0]);
      float o1  = tanh_(att + xo);
      ov2[u] = xo + tanh_(o1);
    }
    float2v o2; o2[0] = ov2[0]; o2[1] = ov2[1];
    *(float2v*)&out[(size_t)eb * (T_ * 512) + (size_t)(T_ - 1) * 512 + fb * 16 + ejp] = o2;
  }
}

// ===== fallback for small ws: round-4 chassis (flags, bf16 ring-4) =====
__global__ __launch_bounds__(256, 1) void k_lstm_fb(
    const float* __restrict__ X,
    const ushort_t* __restrict__ w1, const ushort_t* __restrict__ wih,
    const ushort_t* __restrict__ wcs, const ushort_t* __restrict__ whs,
    const float* __restrict__ bias,
    ushort_t* __restrict__ HN, ushort_t* __restrict__ CN,
    int* __restrict__ flags, float* __restrict__ out)
{
  const int fb   = blockIdx.x;
  const int tid  = threadIdx.x;
  const int wid  = tid >> 6;
  const int lane = tid & 63;
  const int mh   = wid & 1;
  const int ar   = lane & 15;
  const int ko   = (lane >> 4) << 3;

  __shared__ float s_tiles[12][16][20];

  const int eb  = tid >> 3;
  const int ejp = (tid & 7) * 2;
  const int emh = eb >> 4, ebr = eb & 15;
  float bI[2], bF[2], bG[2], bO[2];
  #pragma unroll
  for (int u = 0; u < 2; ++u) {
    bI[u] = bias[0 * 512 + fb * 16 + ejp + u];
    bF[u] = bias[1 * 512 + fb * 16 + ejp + u];
    bG[u] = bias[2 * 512 + fb * 16 + ejp + u];
    bO[u] = bias[3 * 512 + fb * 16 + ejp + u];
  }

  const int gtype0 = wid >> 1;
  const int gtype1 = 2 + (wid >> 1);

  short8v bw0[16], bw1[16], bw2[16];
  {
    const ushort_t* p0 = w1 + ((size_t)(gtype0 * 512 + fb * 16 + ar)) * 512 + ko;
    const ushort_t* p1 = w1 + ((size_t)(gtype1 * 512 + fb * 16 + ar)) * 512 + ko;
    const ushort_t* p2 = ((wid < 2) ? wcs : whs) + ((size_t)(fb * 16 + ar)) * 512 + ko;
    #pragma unroll
    for (int kk = 0; kk < 16; ++kk) {
      bw0[kk] = *(const short8v*)(p0 + (size_t)kk * 32);
      bw1[kk] = *(const short8v*)(p1 + (size_t)kk * 32);
      bw2[kk] = *(const short8v*)(p2 + (size_t)kk * 32);
    }
  }

  const ushort_t* bx0_ = wih + ((size_t)(gtype0 * 512 + fb * 16 + ar)) * 512 + ko;
  const ushort_t* bx1_ = wih + ((size_t)(gtype1 * 512 + fb * 16 + ar)) * 512 + ko;
  const int arow_x = mh * 16 + ar;
  const int t0 = wid, t1 = wid + 4, t2 = wid + 8;

  for (int t = 0; t <= T_; ++t) {
    float4v acc0 = {0.f, 0.f, 0.f, 0.f};
    float4v acc1 = acc0, acc2 = acc0;

    float2v xo2 = {0.f, 0.f};
    if (t > 0)
      xo2 = *(const float2v*)&X[(size_t)eb * (T_ * 512) + (size_t)(t - 1) * 512 + fb * 16 + ejp];

    if (t < T_) {
      const float* xrow = X + (size_t)arow_x * (T_ * 512) + (size_t)t * 512 + ko;
      const ushort_t* bx0 = bx0_;
      const ushort_t* bx1 = bx1_;
      asm volatile("" : "+v"(bx0), "+v"(bx1));
      #pragma unroll
      for (int kk = 0; kk < 16; ++kk) {
        const float* p = xrow + kk * 32;
        float4v xa = *(const float4v*)(p);
        float4v xb = *(const float4v*)(p + 4);
        uint4v ua = __builtin_bit_cast(uint4v, xa);
        uint4v ub = __builtin_bit_cast(uint4v, xb);
        uint4v pk;
        pk[0] = __builtin_amdgcn_perm(ua[1], ua[0], 0x07060302u);
        pk[1] = __builtin_amdgcn_perm(ua[3], ua[2], 0x07060302u);
        pk[2] = __builtin_amdgcn_perm(ub[1], ub[0], 0x07060302u);
        pk[3] = __builtin_amdgcn_perm(ub[3], ub[2], 0x07060302u);
        short8v a = __builtin_bit_cast(short8v, pk);
        short8v b0 = *(const short8v*)(bx0 + (size_t)kk * 32);
        short8v b1 = *(const short8v*)(bx1 + (size_t)kk * 32);
        acc0 = __builtin_amdgcn_mfma_f32_16x16x32_bf16(a, b0, acc0, 0, 0, 0);
        acc1 = __builtin_amdgcn_mfma_f32_16x16x32_bf16(a, b1, acc1, 0, 0, 0);
      }
    }

    if (t > 0) {
      while (true) {
        int v = (lane < NWG)
              ? __hip_atomic_load(flags + lane * 16, __ATOMIC_RELAXED, __HIP_MEMORY_SCOPE_AGENT)
              : t;
        if (__all(v >= t)) break;
      }
      __builtin_amdgcn_sched_barrier(0);
    }

    const int rs = (t + 3) & 3;
    const ushort_t* hb = HN + (size_t)rs * (32 * 512) + (size_t)arow_x * 512 + ko;
    short8v hfrag[16];
    #pragma unroll
    for (int kk = 0; kk < 16; ++kk)
      hfrag[kk] = ld_coh16(hb + (size_t)kk * 32);
    short8v cfrag[16];
    if (wid < 2) {
      const ushort_t* cb2 = CN + (size_t)rs * (32 * 512) + (size_t)arow_x * 512 + ko;
      #pragma unroll
      for (int kk = 0; kk < 16; ++kk)
        cfrag[kk] = ld_coh16(cb2 + (size_t)kk * 32);
    }
    asm volatile("s_waitcnt vmcnt(0)" ::: "memory");
    __builtin_amdgcn_sched_barrier(0);

    #pragma unroll
    for (int kk = 0; kk < 16; ++kk) {
      acc0 = __builtin_amdgcn_mfma_f32_16x16x32_bf16(hfrag[kk], bw0[kk], acc0, 0, 0, 0);
      acc1 = __builtin_amdgcn_mfma_f32_16x16x32_bf16(hfrag[kk], bw1[kk], acc1, 0, 0, 0);
      short8v a2 = (wid < 2) ? cfrag[kk] : hfrag[kk];
      acc2 = __builtin_amdgcn_mfma_f32_16x16x32_bf16(a2, bw2[kk], acc2, 0, 0, 0);
    }

    __syncthreads();

    {
      const int rb = (lane >> 4) << 2, cc = lane & 15;
      #pragma unroll
      for (int r = 0; r < 4; ++r) {
        s_tiles[t0][rb + r][cc] = acc0[r];
        s_tiles[t1][rb + r][cc] = acc1[r];
        s_tiles[t2][rb + r][cc] = acc2[r];
      }
    }
    __syncthreads();

    if (t < T_) {
      unsigned hpk = 0, cpk = 0;
      #pragma unroll
      for (int u = 0; u < 2; ++u) {
        int j = ejp + u;
        float iv  = s_tiles[0 + emh][ebr][j] + bI[u];
        float fv  = s_tiles[2 + emh][ebr][j] + bF[u];
        float gv  = s_tiles[4 + emh][ebr][j] + bG[u];
        float ov  = s_tiles[6 + emh][ebr][j] + bO[u];
        float c2p = s_tiles[8 + emh][ebr][j];
        float cnv = sigm(fv) * c2p + sigm(iv) * tanh_(gv);
        float hnv = sigm(ov) * tanh_(cnv);
        hpk |= ((unsigned)f2bf(hnv)) << (16 * u);
        cpk |= ((unsigned)f2bf(cnv)) << (16 * u);
      }
      size_t uso = (size_t)(t & 3) * (32 * 512) + (size_t)eb * 512 + fb * 16 + ejp;
      __hip_atomic_store((unsigned*)(HN + uso), hpk,
                         __ATOMIC_RELAXED, __HIP_MEMORY_SCOPE_AGENT);
      __hip_atomic_store((unsigned*)(CN + uso), cpk,
                         __ATOMIC_RELAXED, __HIP_MEMORY_SCOPE_AGENT);
    }
    __syncthreads();
    if (t < T_ && tid == 0)
      __hip_atomic_store(flags + fb * 16, t + 1, __ATOMIC_RELAXED, __HIP_MEMORY_SCOPE_AGENT);

    if (t > 0) {
      float ov2[2];
      #pragma unroll
      for (int u = 0; u < 2; ++u) {
        int j = ejp + u;
        float c2p = s_tiles[8 + emh][ebr][j];
        float h2p = s_tiles[10 + emh][ebr][j];
        float att = tanh_(h2p + c2p);
        float xo  = (u ? xo2[1] : xo2[0]);
        float o1  = tanh_(att + xo);
        ov2[u] = xo + tanh_(o1);
      }
      float2v o2; o2[0] = ov2[0]; o2[1] = ov2[1];
      *(float2v*)&out[(size_t)eb * (T_ * 512) + (size_t)(t - 1) * 512 + fb * 16 + ejp] = o2;
    }
  }
}

extern "C" void kernel_launch(void* const* d_in, const int* in_sizes, int n_in,
                              void* d_out, int out_size, void* d_ws, size_t ws_size,
                              hipStream_t stream) {
  const float* X   = (const float*)d_in[0];
  const float* Wih = (const float*)d_in[1];
  const float* Whh = (const float*)d_in[2];
  const float* bih = (const float*)d_in[3];
  const float* bhh = (const float*)d_in[4];
  const float* Whs = (const float*)d_in[5];
  const float* Wcs = (const float*)d_in[6];

  char* ws = (char*)d_ws;
  ushort_t* w1_bf  = (ushort_t*)(ws + 0);        // 2,097,152 B
  ushort_t* wih_bf = (ushort_t*)(ws + 2097152);  // 2,097,152 B
  ushort_t* wcs_bf = (ushort_t*)(ws + 4194304);  //   524,288 B
  ushort_t* whs_bf = (ushort_t*)(ws + 4718592);  //   524,288 B
  float*    bias   = (float*)   (ws + 5242880);  //     8,192 B
  unsigned* HT     = (unsigned*)(ws + 5251072);  //   131,072 B (2-slot tagged ring)
  unsigned* CT     = (unsigned*)(ws + 5382144);  //   131,072 B
  int*      flags  = (int*)     (ws + 5513216);  //     2,048 B (fallback only)
  ushort_t* G      = (ushort_t*)(ws + 5515264);  // 268,435,456 B
  if (ws_size < (size_t)5515264) return;
  const bool pre = ws_size >= (size_t)5515264 + (size_t)268435456;

  k_prep_w1<<<4096, 256, 0, stream>>>(Whh, Whs, w1_bf);
  k_prep_misc<<<2048, 256, 0, stream>>>(Wih, Wcs, Whs, bih, bhh,
                                        wih_bf, wcs_bf, whs_bf, bias, HT, CT, flags);
  if (pre) {
    k_gemm_g<<<16384, 256, 0, stream>>>(X, wih_bf, G);
    k_lstm_tag2<<<NWG, 256, 0, stream>>>(X, w1_bf, wcs_bf, whs_bf, bias, G,
                                         HT, CT, (float*)d_out);
  } else {
    // fallback: reuse HT/CT as bf16 4-slot rings (zeroed fully above)
    k_lstm_fb<<<NWG, 256, 0, stream>>>(X, w1_bf, wih_bf, wcs_bf, whs_bf, bias,
                                       (ushort_t*)HT, (ushort_t*)CT, flags, (float*)d_out);
  }
}

// Round 13
// 16925.925 us; speedup vs baseline: 1.2881x; 1.2881x over previous
//
#include <hip/hip_runtime.h>

#define T_   2048
#define NWG  32

typedef float  float4v __attribute__((ext_vector_type(4)));
typedef float  float2v __attribute__((ext_vector_type(2)));
typedef short  short8v __attribute__((ext_vector_type(8)));
typedef short  short4v __attribute__((ext_vector_type(4)));
typedef unsigned uint4v __attribute__((ext_vector_type(4)));
typedef unsigned short ushort_t;

__device__ __forceinline__ ushort_t f2bf(float f) {
  union { float f; unsigned u; } v; v.f = f;
  unsigned r = (v.u + 0x7FFFu + ((v.u >> 16) & 1u)) >> 16;  // RTN
  return (ushort_t)r;
}
__device__ __forceinline__ float bf2f(short s) {
  union { unsigned u; float f; } v; v.u = ((unsigned)(unsigned short)s) << 16;
  return v.f;
}
__device__ __forceinline__ float sigm(float x) {
  x = fmaxf(x, -30.f);
  return __fdividef(1.f, 1.f + __expf(-x));
}
__device__ __forceinline__ float tanh_(float x) {
  x = fminf(fmaxf(x, -15.f), 15.f);
  float e = __expf(2.f * x);
  return (e - 1.f) * __fdividef(1.f, e + 1.f);
}

// Coherence-point 16B load (bypass L1+L2, no cache-wide invalidate). Plain-
// pipelined; caller must s_waitcnt vmcnt(0) before consuming.
__device__ __forceinline__ short8v ld_coh16(const ushort_t* p) {
  short8v r;
  asm volatile("global_load_dwordx4 %0, %1, off sc0 sc1" : "=v"(r) : "v"(p));
  return r;
}

// W1[n,k] = sum_j W_hh[n,j] * W_hs[j,k]   (fold: h2 @ W_hh^T == h_new @ W1^T)
__global__ void k_prep_w1(const float* __restrict__ Whh, const float* __restrict__ Whs,
                          ushort_t* __restrict__ w1) {
  int idx = blockIdx.x * 256 + threadIdx.x;
  if (idx >= 2048 * 512) return;
  int n = idx >> 9, k = idx & 511;
  const float* whr = Whh + (size_t)n * 512;
  const float* wsk = Whs + k;
  float s = 0.f;
  #pragma unroll 8
  for (int j = 0; j < 512; ++j) s += whr[j] * wsk[(size_t)j * 512];
  w1[idx] = f2bf(s);
}

__global__ void k_prep_misc(const float* __restrict__ Wih, const float* __restrict__ Wcs,
                            const float* __restrict__ Whs, const float* __restrict__ bih,
                            const float* __restrict__ bhh,
                            ushort_t* __restrict__ wih_bf, ushort_t* __restrict__ wcs_bf,
                            ushort_t* __restrict__ whs_bf, float* __restrict__ bias,
                            ushort_t* __restrict__ HN, ushort_t* __restrict__ CN,
                            int* __restrict__ cnt) {
  const int total = 1048576 + 262144 + 262144 + 2048 + 16384 + 16384 + 2048;
  for (int i = blockIdx.x * blockDim.x + threadIdx.x; i < total; i += gridDim.x * blockDim.x) {
    int r = i;
    if (r < 1048576) { wih_bf[r] = f2bf(Wih[r]); continue; }
    r -= 1048576;
    if (r < 262144)  { wcs_bf[r] = f2bf(Wcs[r]); continue; }
    r -= 262144;
    if (r < 262144)  { whs_bf[r] = f2bf(Whs[r]); continue; }
    r -= 262144;
    if (r < 2048)    { bias[r] = bih[r] + bhh[r]; continue; }
    r -= 2048;
    if (r < 16384)   { HN[3 * 16384 + r] = 0; continue; }   // zero ring slot 3 (state t=-1)
    r -= 16384;
    if (r < 16384)   { CN[3 * 16384 + r] = 0; continue; }
    r -= 16384;
    cnt[r] = 0;   // 2048 ints: 128 per-wave flag slots, 64B-padded
  }
}

// G[t][fb][gate][col][batch] = (X_t @ Wih^T) in MFMA C-fragment order, bf16.
__global__ __launch_bounds__(256) void k_gemm_g(
    const float* __restrict__ X, const ushort_t* __restrict__ wih,
    ushort_t* __restrict__ G) {
  const int bid = blockIdx.x;
  const int fb  = bid & 31;
  const int tg  = bid >> 5;
  const int wid = threadIdx.x >> 6;
  const int lane = threadIdx.x & 63;
  const int t   = tg * 4 + wid;
  const int ar  = lane & 15;
  const int ko  = (lane >> 4) << 3;

  float4v acc[2][4];
  #pragma unroll
  for (int mh = 0; mh < 2; ++mh)
    #pragma unroll
    for (int cg = 0; cg < 4; ++cg)
      acc[mh][cg] = float4v{0.f, 0.f, 0.f, 0.f};

  #pragma unroll 4
  for (int kk = 0; kk < 16; ++kk) {
    short8v a[2];
    #pragma unroll
    for (int mh = 0; mh < 2; ++mh) {
      const float* p = X + (size_t)(mh * 16 + ar) * (T_ * 512) + (size_t)t * 512 + kk * 32 + ko;
      float4v xa = *(const float4v*)(p);
      float4v xb = *(const float4v*)(p + 4);
      uint4v ua = __builtin_bit_cast(uint4v, xa);
      uint4v ub = __builtin_bit_cast(uint4v, xb);
      uint4v pk;
      pk[0] = __builtin_amdgcn_perm(ua[1], ua[0], 0x07060302u);
      pk[1] = __builtin_amdgcn_perm(ua[3], ua[2], 0x07060302u);
      pk[2] = __builtin_amdgcn_perm(ub[1], ub[0], 0x07060302u);
      pk[3] = __builtin_amdgcn_perm(ub[3], ub[2], 0x07060302u);
      a[mh] = __builtin_bit_cast(short8v, pk);
    }
    #pragma unroll
    for (int cg = 0; cg < 4; ++cg) {
      short8v b = *(const short8v*)(wih + ((size_t)(cg * 512 + fb * 16 + ar)) * 512 + kk * 32 + ko);
      acc[0][cg] = __builtin_amdgcn_mfma_f32_16x16x32_bf16(a[0], b, acc[0][cg], 0, 0, 0);
      acc[1][cg] = __builtin_amdgcn_mfma_f32_16x16x32_bf16(a[1], b, acc[1][cg], 0, 0, 0);
    }
  }

  const size_t base = ((size_t)t * 32 + fb) * 2048;
  #pragma unroll
  for (int mh = 0; mh < 2; ++mh)
    #pragma unroll
    for (int cg = 0; cg < 4; ++cg) {
      short4v s;
      #pragma unroll
      for (int r = 0; r < 4; ++r) s[r] = (short)f2bf(acc[mh][cg][r]);
      *(short4v*)(G + base + cg * 512 + ar * 32 + mh * 16 + ((lane >> 4) << 2)) = s;
    }
}

// ===== main: round-11 chassis (dbuf tiles, 1 barrier, out-hoist t-2) with
// PER-WAVE PLAIN FLAG signal (no barrier3, no RMW):
//   producer wave: elementwise -> stores -> own vmcnt(0) -> flags[fb*4+wid]=t+1
//   consumer: each lane polls 2 of the 128 padded flag slots.
__global__ __launch_bounds__(256, 1) void k_lstm_pre(
    const float* __restrict__ X,
    const ushort_t* __restrict__ w1,
    const ushort_t* __restrict__ wcs, const ushort_t* __restrict__ whs,
    const float* __restrict__ bias, const ushort_t* __restrict__ G,
    ushort_t* __restrict__ HN, ushort_t* __restrict__ CN,
    int* __restrict__ cnt, float* __restrict__ out)
{
  const int fb   = blockIdx.x;
  const int tid  = threadIdx.x;
  const int wid  = tid >> 6;
  const int lane = tid & 63;
  const int mh   = wid & 1;
  const int ar   = lane & 15;
  const int ko   = (lane >> 4) << 3;

  __shared__ float s_tiles[2][12][16][20];   // double-buffered by t&1

  const int eb  = tid >> 3;
  const int ejp = (tid & 7) * 2;
  const int emh = eb >> 4, ebr = eb & 15;
  float bI[2], bF[2], bG[2], bO[2];
  #pragma unroll
  for (int u = 0; u < 2; ++u) {
    bI[u] = bias[0 * 512 + fb * 16 + ejp + u];
    bF[u] = bias[1 * 512 + fb * 16 + ejp + u];
    bG[u] = bias[2 * 512 + fb * 16 + ejp + u];
    bO[u] = bias[3 * 512 + fb * 16 + ejp + u];
  }

  const int gtype0 = wid >> 1;
  const int gtype1 = 2 + (wid >> 1);

  // state-pass B fragments: load ONCE into registers (AGPR-backed)
  short8v bw0[16], bw1[16], bw2[16];
  {
    const ushort_t* p0 = w1 + ((size_t)(gtype0 * 512 + fb * 16 + ar)) * 512 + ko;
    const ushort_t* p1 = w1 + ((size_t)(gtype1 * 512 + fb * 16 + ar)) * 512 + ko;
    const ushort_t* p2 = ((wid < 2) ? wcs : whs) + ((size_t)(fb * 16 + ar)) * 512 + ko;
    #pragma unroll
    for (int kk = 0; kk < 16; ++kk) {
      bw0[kk] = *(const short8v*)(p0 + (size_t)kk * 32);
      bw1[kk] = *(const short8v*)(p1 + (size_t)kk * 32);
      bw2[kk] = *(const short8v*)(p2 + (size_t)kk * 32);
    }
  }

  const int arow_x = mh * 16 + ar;
  const int t0 = wid, t1 = wid + 4, t2 = wid + 8;
  const int glo = ((lane >> 4) << 2) + mh * 16 + ar * 32;

  short4v gp0, gp1;
  {   // prologue G prefetch for t=0
    const ushort_t* gb = G + (size_t)fb * 2048 + glo;
    gp0 = *(const short4v*)(gb + gtype0 * 512);
    gp1 = *(const short4v*)(gb + gtype1 * 512);
  }

  for (int t = 0; t <= T_; ++t) {
    // ---- prefetch output-pass X for step t-2 (off the sync path) ----
    float2v xo2 = {0.f, 0.f};
    if (t >= 2)
      xo2 = *(const float2v*)&X[(size_t)eb * (T_ * 512) + (size_t)(t - 2) * 512 + fb * 16 + ejp];

    // ---- poll the 128 per-wave flags (each lane checks 2 padded slots) ----
    if (t > 0) {
      while (true) {
        int v0 = __hip_atomic_load(cnt + lane * 16, __ATOMIC_RELAXED, __HIP_MEMORY_SCOPE_AGENT);
        int v1 = __hip_atomic_load(cnt + (64 + lane) * 16, __ATOMIC_RELAXED, __HIP_MEMORY_SCOPE_AGENT);
        if (__all((v0 >= t) && (v1 >= t))) break;
      }
      __builtin_amdgcn_sched_barrier(0);
    }

    // ---- ISSUE state A-fragment loads (async, pipelined) ----
    const int rs = (t + 3) & 3;
    const ushort_t* hb = HN + (size_t)rs * (32 * 512) + (size_t)arow_x * 512 + ko;
    short8v hfrag[16];
    #pragma unroll
    for (int kk = 0; kk < 16; ++kk)
      hfrag[kk] = ld_coh16(hb + (size_t)kk * 32);
    short8v cfrag[16];
    if (wid < 2) {
      const ushort_t* cb = CN + (size_t)rs * (32 * 512) + (size_t)arow_x * 512 + ko;
      #pragma unroll
      for (int kk = 0; kk < 16; ++kk)
        cfrag[kk] = ld_coh16(cb + (size_t)kk * 32);
    }
    __builtin_amdgcn_sched_barrier(0);   // keep the work below AFTER load issue

    // ---- work hidden under the state-load latency ----
    // (a) init gate accumulators from prefetched G
    float4v acc0, acc1, acc2;
    #pragma unroll
    for (int r = 0; r < 4; ++r) {
      acc0[r] = bf2f(gp0[r]);
      acc1[r] = bf2f(gp1[r]);
      acc2[r] = 0.f;
    }
    // (b) output pass for step t-2 (reads buffer (t-1)&1 = c2/h2 of step t-2;
    //     VALU+LDS only; store deferred to after the signal)
    float ov2[2];
    if (t >= 2) {
      const int p = (t - 1) & 1;
      #pragma unroll
      for (int u = 0; u < 2; ++u) {
        int j = ejp + u;
        float c2p = s_tiles[p][8 + emh][ebr][j];
        float h2p = s_tiles[p][10 + emh][ebr][j];
        float att = tanh_(h2p + c2p);
        float xo  = (u ? xo2[1] : xo2[0]);
        float o1  = tanh_(att + xo);
        ov2[u] = xo + tanh_(o1);
      }
    }

    asm volatile("s_waitcnt vmcnt(0)" ::: "memory");
    __builtin_amdgcn_sched_barrier(0);     // MFMAs must not hoist above the wait

    // ---- state MFMA: A and B from registers ----
    #pragma unroll
    for (int kk = 0; kk < 16; ++kk) {
      acc0 = __builtin_amdgcn_mfma_f32_16x16x32_bf16(hfrag[kk], bw0[kk], acc0, 0, 0, 0);
      acc1 = __builtin_amdgcn_mfma_f32_16x16x32_bf16(hfrag[kk], bw1[kk], acc1, 0, 0, 0);
      short8v a2 = (wid < 2) ? cfrag[kk] : hfrag[kk];
      acc2 = __builtin_amdgcn_mfma_f32_16x16x32_bf16(a2, bw2[kk], acc2, 0, 0, 0);
    }

    // ---- C tiles -> LDS (buffer t&1) ----
    const int pb = t & 1;
    {
      const int rb = (lane >> 4) << 2, cc = lane & 15;
      #pragma unroll
      for (int r = 0; r < 4; ++r) {
        s_tiles[pb][t0][rb + r][cc] = acc0[r];
        s_tiles[pb][t1][rb + r][cc] = acc1[r];
        s_tiles[pb][t2][rb + r][cc] = acc2[r];
      }
    }
    __syncthreads();   // the ONE barrier per step: tiles visible

    // ---- elementwise cell update + state store + PER-WAVE plain flag ----
    if (t < T_) {
      unsigned hpk = 0, cpk = 0;
      #pragma unroll
      for (int u = 0; u < 2; ++u) {
        int j = ejp + u;
        float iv  = s_tiles[pb][0 + emh][ebr][j] + bI[u];
        float fv  = s_tiles[pb][2 + emh][ebr][j] + bF[u];
        float gv  = s_tiles[pb][4 + emh][ebr][j] + bG[u];
        float ov  = s_tiles[pb][6 + emh][ebr][j] + bO[u];
        float c2p = s_tiles[pb][8 + emh][ebr][j];
        float cnv = sigm(fv) * c2p + sigm(iv) * tanh_(gv);
        float hnv = sigm(ov) * tanh_(cnv);
        hpk |= ((unsigned)f2bf(hnv)) << (16 * u);
        cpk |= ((unsigned)f2bf(cnv)) << (16 * u);
      }
      size_t uso = (size_t)(t & 3) * (32 * 512) + (size_t)eb * 512 + fb * 16 + ejp;
      __hip_atomic_store((unsigned*)(HN + uso), hpk,
                         __ATOMIC_RELAXED, __HIP_MEMORY_SCOPE_AGENT);
      __hip_atomic_store((unsigned*)(CN + uso), cpk,
                         __ATOMIC_RELAXED, __HIP_MEMORY_SCOPE_AGENT);
      // per-wave: drain own stores, then one PLAIN flag store per wave
      asm volatile("s_waitcnt vmcnt(0)" ::: "memory");
      if ((tid & 63) == 0)
        __hip_atomic_store(cnt + (fb * 4 + wid) * 16, t + 1,
                           __ATOMIC_RELAXED, __HIP_MEMORY_SCOPE_AGENT);
    }

    // ---- deferred out store for step t-2 (off the critical path) ----
    if (t >= 2) {
      float2v o2; o2[0] = ov2[0]; o2[1] = ov2[1];
      *(float2v*)&out[(size_t)eb * (T_ * 512) + (size_t)(t - 2) * 512 + fb * 16 + ejp] = o2;
    }

    // ---- prefetch next step's G fragment (in flight across next poll) ----
    if (t + 1 < T_) {
      const ushort_t* gb = G + ((size_t)((t + 1) * 32 + fb)) * 2048 + glo;
      gp0 = *(const short4v*)(gb + gtype0 * 512);
      gp1 = *(const short4v*)(gb + gtype1 * 512);
    }
  }

  // ---- epilogue: output for step T_-1 (tiles in buffer T_&1, barrier'd) ----
  {
    const int p = T_ & 1;
    float2v xo2 = *(const float2v*)&X[(size_t)eb * (T_ * 512) + (size_t)(T_ - 1) * 512 + fb * 16 + ejp];
    float ov2[2];
    #pragma unroll
    for (int u = 0; u < 2; ++u) {
      int j = ejp + u;
      float c2p = s_tiles[p][8 + emh][ebr][j];
      float h2p = s_tiles[p][10 + emh][ebr][j];
      float att = tanh_(h2p + c2p);
      float xo  = (u ? xo2[1] : xo2[0]);
      float o1  = tanh_(att + xo);
      ov2[u] = xo + tanh_(o1);
    }
    float2v o2; o2[0] = ov2[0]; o2[1] = ov2[1];
    *(float2v*)&out[(size_t)eb * (T_ * 512) + (size_t)(T_ - 1) * 512 + fb * 16 + ejp] = o2;
  }
}

// ===== fallback for small ws: verbatim round-4 chassis (proven) =====
__global__ __launch_bounds__(256, 1) void k_lstm_fb(
    const float* __restrict__ X,
    const ushort_t* __restrict__ w1, const ushort_t* __restrict__ wih,
    const ushort_t* __restrict__ wcs, const ushort_t* __restrict__ whs,
    const float* __restrict__ bias,
    ushort_t* __restrict__ HN, ushort_t* __restrict__ CN,
    int* __restrict__ flags, float* __restrict__ out)
{
  const int fb   = blockIdx.x;
  const int tid  = threadIdx.x;
  const int wid  = tid >> 6;
  const int lane = tid & 63;
  const int mh   = wid & 1;
  const int ar   = lane & 15;
  const int ko   = (lane >> 4) << 3;

  __shared__ float s_tiles[12][16][20];

  const int eb  = tid >> 3;
  const int ejp = (tid & 7) * 2;
  const int emh = eb >> 4, ebr = eb & 15;
  float bI[2], bF[2], bG[2], bO[2];
  #pragma unroll
  for (int u = 0; u < 2; ++u) {
    bI[u] = bias[0 * 512 + fb * 16 + ejp + u];
    bF[u] = bias[1 * 512 + fb * 16 + ejp + u];
    bG[u] = bias[2 * 512 + fb * 16 + ejp + u];
    bO[u] = bias[3 * 512 + fb * 16 + ejp + u];
  }

  const int gtype0 = wid >> 1;
  const int gtype1 = 2 + (wid >> 1);

  short8v bw0[16], bw1[16], bw2[16];
  {
    const ushort_t* p0 = w1 + ((size_t)(gtype0 * 512 + fb * 16 + ar)) * 512 + ko;
    const ushort_t* p1 = w1 + ((size_t)(gtype1 * 512 + fb * 16 + ar)) * 512 + ko;
    const ushort_t* p2 = ((wid < 2) ? wcs : whs) + ((size_t)(fb * 16 + ar)) * 512 + ko;
    #pragma unroll
    for (int kk = 0; kk < 16; ++kk) {
      bw0[kk] = *(const short8v*)(p0 + (size_t)kk * 32);
      bw1[kk] = *(const short8v*)(p1 + (size_t)kk * 32);
      bw2[kk] = *(const short8v*)(p2 + (size_t)kk * 32);
    }
  }

  const ushort_t* bx0_ = wih + ((size_t)(gtype0 * 512 + fb * 16 + ar)) * 512 + ko;
  const ushort_t* bx1_ = wih + ((size_t)(gtype1 * 512 + fb * 16 + ar)) * 512 + ko;
  const int arow_x = mh * 16 + ar;
  const int t0 = wid, t1 = wid + 4, t2 = wid + 8;

  for (int t = 0; t <= T_; ++t) {
    float4v acc0 = {0.f, 0.f, 0.f, 0.f};
    float4v acc1 = acc0, acc2 = acc0;

    float2v xo2 = {0.f, 0.f};
    if (t > 0)
      xo2 = *(const float2v*)&X[(size_t)eb * (T_ * 512) + (size_t)(t - 1) * 512 + fb * 16 + ejp];

    if (t < T_) {
      const float* xrow = X + (size_t)arow_x * (T_ * 512) + (size_t)t * 512 + ko;
      const ushort_t* bx0 = bx0_;
      const ushort_t* bx1 = bx1_;
      asm volatile("" : "+v"(bx0), "+v"(bx1));
      #pragma unroll
      for (int kk = 0; kk < 16; ++kk) {
        const float* p = xrow + kk * 32;
        float4v xa = *(const float4v*)(p);
        float4v xb = *(const float4v*)(p + 4);
        uint4v ua = __builtin_bit_cast(uint4v, xa);
        uint4v ub = __builtin_bit_cast(uint4v, xb);
        uint4v pk;
        pk[0] = __builtin_amdgcn_perm(ua[1], ua[0], 0x07060302u);
        pk[1] = __builtin_amdgcn_perm(ua[3], ua[2], 0x07060302u);
        pk[2] = __builtin_amdgcn_perm(ub[1], ub[0], 0x07060302u);
        pk[3] = __builtin_amdgcn_perm(ub[3], ub[2], 0x07060302u);
        short8v a = __builtin_bit_cast(short8v, pk);
        short8v b0 = *(const short8v*)(bx0 + (size_t)kk * 32);
        short8v b1 = *(const short8v*)(bx1 + (size_t)kk * 32);
        acc0 = __builtin_amdgcn_mfma_f32_16x16x32_bf16(a, b0, acc0, 0, 0, 0);
        acc1 = __builtin_amdgcn_mfma_f32_16x16x32_bf16(a, b1, acc1, 0, 0, 0);
      }
    }

    if (t > 0) {
      while (true) {
        int v = (lane < NWG)
              ? __hip_atomic_load(flags + lane * 16, __ATOMIC_RELAXED, __HIP_MEMORY_SCOPE_AGENT)
              : t;
        if (__all(v >= t)) break;
      }
      __builtin_amdgcn_sched_barrier(0);
    }

    const int rs = (t + 3) & 3;
    const ushort_t* hb = HN + (size_t)rs * (32 * 512) + (size_t)arow_x * 512 + ko;
    short8v hfrag[16];
    #pragma unroll
    for (int kk = 0; kk < 16; ++kk)
      hfrag[kk] = ld_coh16(hb + (size_t)kk * 32);
    short8v cfrag[16];
    if (wid < 2) {
      const ushort_t* cb = CN + (size_t)rs * (32 * 512) + (size_t)arow_x * 512 + ko;
      #pragma unroll
      for (int kk = 0; kk < 16; ++kk)
        cfrag[kk] = ld_coh16(cb + (size_t)kk * 32);
    }
    asm volatile("s_waitcnt vmcnt(0)" ::: "memory");
    __builtin_amdgcn_sched_barrier(0);

    #pragma unroll
    for (int kk = 0; kk < 16; ++kk) {
      acc0 = __builtin_amdgcn_mfma_f32_16x16x32_bf16(hfrag[kk], bw0[kk], acc0, 0, 0, 0);
      acc1 = __builtin_amdgcn_mfma_f32_16x16x32_bf16(hfrag[kk], bw1[kk], acc1, 0, 0, 0);
      short8v a2 = (wid < 2) ? cfrag[kk] : hfrag[kk];
      acc2 = __builtin_amdgcn_mfma_f32_16x16x32_bf16(a2, bw2[kk], acc2, 0, 0, 0);
    }

    __syncthreads();

    {
      const int rb = (lane >> 4) << 2, cc = lane & 15;
      #pragma unroll
      for (int r = 0; r < 4; ++r) {
        s_tiles[t0][rb + r][cc] = acc0[r];
        s_tiles[t1][rb + r][cc] = acc1[r];
        s_tiles[t2][rb + r][cc] = acc2[r];
      }
    }
    __syncthreads();

    if (t < T_) {
      unsigned hpk = 0, cpk = 0;
      #pragma unroll
      for (int u = 0; u < 2; ++u) {
        int j = ejp + u;
        float iv  = s_tiles[0 + emh][ebr][j] + bI[u];
        float fv  = s_tiles[2 + emh][ebr][j] + bF[u];
        float gv  = s_tiles[4 + emh][ebr][j] + bG[u];
        float ov  = s_tiles[6 + emh][ebr][j] + bO[u];
        float c2p = s_tiles[8 + emh][ebr][j];
        float cnv = sigm(fv) * c2p + sigm(iv) * tanh_(gv);
        float hnv = sigm(ov) * tanh_(cnv);
        hpk |= ((unsigned)f2bf(hnv)) << (16 * u);
        cpk |= ((unsigned)f2bf(cnv)) << (16 * u);
      }
      size_t uso = (size_t)(t & 3) * (32 * 512) + (size_t)eb * 512 + fb * 16 + ejp;
      __hip_atomic_store((unsigned*)(HN + uso), hpk,
                         __ATOMIC_RELAXED, __HIP_MEMORY_SCOPE_AGENT);
      __hip_atomic_store((unsigned*)(CN + uso), cpk,
                         __ATOMIC_RELAXED, __HIP_MEMORY_SCOPE_AGENT);
    }
    __syncthreads();
    if (t < T_ && tid == 0)
      __hip_atomic_store(flags + fb * 16, t + 1, __ATOMIC_RELAXED, __HIP_MEMORY_SCOPE_AGENT);

    if (t > 0) {
      float ov2[2];
      #pragma unroll
      for (int u = 0; u < 2; ++u) {
        int j = ejp + u;
        float c2p = s_tiles[8 + emh][ebr][j];
        float h2p = s_tiles[10 + emh][ebr][j];
        float att = tanh_(h2p + c2p);
        float xo  = (u ? xo2[1] : xo2[0]);
        float o1  = tanh_(att + xo);
        ov2[u] = xo + tanh_(o1);
      }
      float2v o2; o2[0] = ov2[0]; o2[1] = ov2[1];
      *(float2v*)&out[(size_t)eb * (T_ * 512) + (size_t)(t - 1) * 512 + fb * 16 + ejp] = o2;
    }
  }
}

extern "C" void kernel_launch(void* const* d_in, const int* in_sizes, int n_in,
                              void* d_out, int out_size, void* d_ws, size_t ws_size,
                              hipStream_t stream) {
  const float* X   = (const float*)d_in[0];
  const float* Wih = (const float*)d_in[1];
  const float* Whh = (const float*)d_in[2];
  const float* bih = (const float*)d_in[3];
  const float* bhh = (const float*)d_in[4];
  const float* Whs = (const float*)d_in[5];
  const float* Wcs = (const float*)d_in[6];

  char* ws = (char*)d_ws;
  ushort_t* w1_bf  = (ushort_t*)(ws + 0);        // 2,097,152 B
  ushort_t* wih_bf = (ushort_t*)(ws + 2097152);  // 2,097,152 B
  ushort_t* wcs_bf = (ushort_t*)(ws + 4194304);  //   524,288 B
  ushort_t* whs_bf = (ushort_t*)(ws + 4718592);  //   524,288 B
  float*    bias   = (float*)   (ws + 5242880);  //     8,192 B
  ushort_t* HN     = (ushort_t*)(ws + 5251072);  //   131,072 B (4-slot ring)
  ushort_t* CN     = (ushort_t*)(ws + 5382144);  //   131,072 B
  int*      cnt    = (int*)     (ws + 5513216);  //     8,192 B (128 padded per-wave flags)
  ushort_t* G      = (ushort_t*)(ws + 5521408);  // 268,435,456 B (optional)
  if (ws_size < (size_t)5521408) return;
  const bool pre = ws_size >= (size_t)5521408 + (size_t)268435456;

  k_prep_w1<<<4096, 256, 0, stream>>>(Whh, Whs, w1_bf);
  k_prep_misc<<<2048, 256, 0, stream>>>(Wih, Wcs, Whs, bih, bhh,
                                        wih_bf, wcs_bf, whs_bf, bias, HN, CN, cnt);
  if (pre) {
    k_gemm_g<<<16384, 256, 0, stream>>>(X, wih_bf, G);
    k_lstm_pre<<<NWG, 256, 0, stream>>>(X, w1_bf, wcs_bf, whs_bf, bias, G,
                                        HN, CN, cnt, (float*)d_out);
  } else {
    k_lstm_fb<<<NWG, 256, 0, stream>>>(X, w1_bf, wih_bf, wcs_bf, whs_bf, bias,
                                       HN, CN, cnt, (float*)d_out);
  }
}

// Round 14
// 11442.243 us; speedup vs baseline: 1.9055x; 1.4792x over previous
//
#include <hip/hip_runtime.h>

#define T_   2048
#define NWG  32

typedef float  float4v __attribute__((ext_vector_type(4)));
typedef float  float2v __attribute__((ext_vector_type(2)));
typedef short  short8v __attribute__((ext_vector_type(8)));
typedef short  short4v __attribute__((ext_vector_type(4)));
typedef unsigned uint4v __attribute__((ext_vector_type(4)));
typedef unsigned short ushort_t;

__device__ __forceinline__ ushort_t f2bf(float f) {
  union { float f; unsigned u; } v; v.f = f;
  unsigned r = (v.u + 0x7FFFu + ((v.u >> 16) & 1u)) >> 16;  // RTN
  return (ushort_t)r;
}
__device__ __forceinline__ float bf2f(short s) {
  union { unsigned u; float f; } v; v.u = ((unsigned)(unsigned short)s) << 16;
  return v.f;
}
__device__ __forceinline__ float sigm(float x) {
  x = fmaxf(x, -30.f);
  return __fdividef(1.f, 1.f + __expf(-x));
}
__device__ __forceinline__ float tanh_(float x) {
  x = fminf(fmaxf(x, -15.f), 15.f);
  float e = __expf(2.f * x);
  return (e - 1.f) * __fdividef(1.f, e + 1.f);
}

// Coherence-point 16B load (bypass L1+L2, no cache-wide invalidate). Plain-
// pipelined; caller must s_waitcnt vmcnt(0) before consuming.
__device__ __forceinline__ short8v ld_coh16(const ushort_t* p) {
  short8v r;
  asm volatile("global_load_dwordx4 %0, %1, off sc0 sc1" : "=v"(r) : "v"(p));
  return r;
}

// W1[n,k] = sum_j W_hh[n,j] * W_hs[j,k]   (fold: h2 @ W_hh^T == h_new @ W1^T)
__global__ void k_prep_w1(const float* __restrict__ Whh, const float* __restrict__ Whs,
                          ushort_t* __restrict__ w1) {
  int idx = blockIdx.x * 256 + threadIdx.x;
  if (idx >= 2048 * 512) return;
  int n = idx >> 9, k = idx & 511;
  const float* whr = Whh + (size_t)n * 512;
  const float* wsk = Whs + k;
  float s = 0.f;
  #pragma unroll 8
  for (int j = 0; j < 512; ++j) s += whr[j] * wsk[(size_t)j * 512];
  w1[idx] = f2bf(s);
}

__global__ void k_prep_misc(const float* __restrict__ Wih, const float* __restrict__ Wcs,
                            const float* __restrict__ Whs, const float* __restrict__ bih,
                            const float* __restrict__ bhh,
                            ushort_t* __restrict__ wih_bf, ushort_t* __restrict__ wcs_bf,
                            ushort_t* __restrict__ whs_bf, float* __restrict__ bias,
                            ushort_t* __restrict__ HN, ushort_t* __restrict__ CN,
                            int* __restrict__ flags) {
  const int total = 1048576 + 262144 + 262144 + 2048 + 16384 + 16384 + 512;
  for (int i = blockIdx.x * blockDim.x + threadIdx.x; i < total; i += gridDim.x * blockDim.x) {
    int r = i;
    if (r < 1048576) { wih_bf[r] = f2bf(Wih[r]); continue; }
    r -= 1048576;
    if (r < 262144)  { wcs_bf[r] = f2bf(Wcs[r]); continue; }
    r -= 262144;
    if (r < 262144)  { whs_bf[r] = f2bf(Whs[r]); continue; }
    r -= 262144;
    if (r < 2048)    { bias[r] = bih[r] + bhh[r]; continue; }
    r -= 2048;
    if (r < 16384)   { HN[3 * 16384 + r] = 0; continue; }   // zero ring slot 3 (state t=-1)
    r -= 16384;
    if (r < 16384)   { CN[3 * 16384 + r] = 0; continue; }
    r -= 16384;
    flags[r] = 0;   // 512 ints: 64B-padded flag slots
  }
}

// G[t][fb][gate][col][batch] = (X_t @ Wih^T) in MFMA C-fragment order, bf16.
// bid = tg*32 + fb (tg-major: the 32 fb-blocks sharing X_t are adjacent ->
// spread round-robin over XCDs, each XCD's L2 fetches X_t once).
// Wave wid computes t = tg*4 + wid.
__global__ __launch_bounds__(256) void k_gemm_g(
    const float* __restrict__ X, const ushort_t* __restrict__ wih,
    ushort_t* __restrict__ G) {
  const int bid = blockIdx.x;
  const int fb  = bid & 31;
  const int tg  = bid >> 5;
  const int wid = threadIdx.x >> 6;
  const int lane = threadIdx.x & 63;
  const int t   = tg * 4 + wid;
  const int ar  = lane & 15;
  const int ko  = (lane >> 4) << 3;

  float4v acc[2][4];
  #pragma unroll
  for (int mh = 0; mh < 2; ++mh)
    #pragma unroll
    for (int cg = 0; cg < 4; ++cg)
      acc[mh][cg] = float4v{0.f, 0.f, 0.f, 0.f};

  #pragma unroll 4
  for (int kk = 0; kk < 16; ++kk) {
    short8v a[2];
    #pragma unroll
    for (int mh = 0; mh < 2; ++mh) {
      const float* p = X + (size_t)(mh * 16 + ar) * (T_ * 512) + (size_t)t * 512 + kk * 32 + ko;
      float4v xa = *(const float4v*)(p);
      float4v xb = *(const float4v*)(p + 4);
      uint4v ua = __builtin_bit_cast(uint4v, xa);
      uint4v ub = __builtin_bit_cast(uint4v, xb);
      uint4v pk;
      pk[0] = __builtin_amdgcn_perm(ua[1], ua[0], 0x07060302u);
      pk[1] = __builtin_amdgcn_perm(ua[3], ua[2], 0x07060302u);
      pk[2] = __builtin_amdgcn_perm(ub[1], ub[0], 0x07060302u);
      pk[3] = __builtin_amdgcn_perm(ub[3], ub[2], 0x07060302u);
      a[mh] = __builtin_bit_cast(short8v, pk);
    }
    #pragma unroll
    for (int cg = 0; cg < 4; ++cg) {
      short8v b = *(const short8v*)(wih + ((size_t)(cg * 512 + fb * 16 + ar)) * 512 + kk * 32 + ko);
      acc[0][cg] = __builtin_amdgcn_mfma_f32_16x16x32_bf16(a[0], b, acc[0][cg], 0, 0, 0);
      acc[1][cg] = __builtin_amdgcn_mfma_f32_16x16x32_bf16(a[1], b, acc[1][cg], 0, 0, 0);
    }
  }

  const size_t base = ((size_t)t * 32 + fb) * 2048;
  #pragma unroll
  for (int mh = 0; mh < 2; ++mh)
    #pragma unroll
    for (int cg = 0; cg < 4; ++cg) {
      short4v s;
      #pragma unroll
      for (int r = 0; r < 4; ++r) s[r] = (short)f2bf(acc[mh][cg][r]);
      *(short4v*)(G + base + cg * 512 + ar * 32 + mh * 16 + ((lane >> 4) << 2)) = s;
    }
}

// ===== persistent kernel, PRE path: round-7 verbatim (best measured) =====
// Round-4 chassis (plain 32-WG grid, agent-scope padded flags, sc0sc1 state
// loads) with the x-pass deleted and a 1-step-ahead G prefetch instead.
__global__ __launch_bounds__(256, 1) void k_lstm_pre(
    const float* __restrict__ X,
    const ushort_t* __restrict__ w1,
    const ushort_t* __restrict__ wcs, const ushort_t* __restrict__ whs,
    const float* __restrict__ bias, const ushort_t* __restrict__ G,
    ushort_t* __restrict__ HN, ushort_t* __restrict__ CN,
    int* __restrict__ flags, float* __restrict__ out)
{
  const int fb   = blockIdx.x;
  const int tid  = threadIdx.x;
  const int wid  = tid >> 6;
  const int lane = tid & 63;
  const int mh   = wid & 1;
  const int ar   = lane & 15;
  const int ko   = (lane >> 4) << 3;

  __shared__ float s_tiles[12][16][20];

  const int eb  = tid >> 3;
  const int ejp = (tid & 7) * 2;
  const int emh = eb >> 4, ebr = eb & 15;
  float bI[2], bF[2], bG[2], bO[2];
  #pragma unroll
  for (int u = 0; u < 2; ++u) {
    bI[u] = bias[0 * 512 + fb * 16 + ejp + u];
    bF[u] = bias[1 * 512 + fb * 16 + ejp + u];
    bG[u] = bias[2 * 512 + fb * 16 + ejp + u];
    bO[u] = bias[3 * 512 + fb * 16 + ejp + u];
  }

  const int gtype0 = wid >> 1;
  const int gtype1 = 2 + (wid >> 1);

  // state-pass B fragments: load ONCE into registers
  short8v bw0[16], bw1[16], bw2[16];
  {
    const ushort_t* p0 = w1 + ((size_t)(gtype0 * 512 + fb * 16 + ar)) * 512 + ko;
    const ushort_t* p1 = w1 + ((size_t)(gtype1 * 512 + fb * 16 + ar)) * 512 + ko;
    const ushort_t* p2 = ((wid < 2) ? wcs : whs) + ((size_t)(fb * 16 + ar)) * 512 + ko;
    #pragma unroll
    for (int kk = 0; kk < 16; ++kk) {
      bw0[kk] = *(const short8v*)(p0 + (size_t)kk * 32);
      bw1[kk] = *(const short8v*)(p1 + (size_t)kk * 32);
      bw2[kk] = *(const short8v*)(p2 + (size_t)kk * 32);
    }
  }

  const int arow_x = mh * 16 + ar;
  const int t0 = wid, t1 = wid + 4, t2 = wid + 8;
  const int glo = ((lane >> 4) << 2) + mh * 16 + ar * 32;   // per-lane G offset

  short4v gp0, gp1;
  {   // prologue prefetch for t=0
    const ushort_t* gb = G + (size_t)fb * 2048 + glo;
    gp0 = *(const short4v*)(gb + gtype0 * 512);
    gp1 = *(const short4v*)(gb + gtype1 * 512);
  }

  for (int t = 0; t <= T_; ++t) {
    // ---- prefetch output-pass X early (off the sync path) ----
    float2v xo2 = {0.f, 0.f};
    if (t > 0)
      xo2 = *(const float2v*)&X[(size_t)eb * (T_ * 512) + (size_t)(t - 1) * 512 + fb * 16 + ejp];

    // ---- poll (agent-scope relaxed atomic, padded flag slots) ----
    if (t > 0) {
      while (true) {
        int v = (lane < NWG)
              ? __hip_atomic_load(flags + lane * 16, __ATOMIC_RELAXED, __HIP_MEMORY_SCOPE_AGENT)
              : t;
        if (__all(v >= t)) break;
      }
      __builtin_amdgcn_sched_barrier(0);
    }

    // ---- state A-fragments: pipelined coherence-point loads ----
    const int rs = (t + 3) & 3;
    const ushort_t* hb = HN + (size_t)rs * (32 * 512) + (size_t)arow_x * 512 + ko;
    short8v hfrag[16];
    #pragma unroll
    for (int kk = 0; kk < 16; ++kk)
      hfrag[kk] = ld_coh16(hb + (size_t)kk * 32);
    short8v cfrag[16];
    if (wid < 2) {
      const ushort_t* cb = CN + (size_t)rs * (32 * 512) + (size_t)arow_x * 512 + ko;
      #pragma unroll
      for (int kk = 0; kk < 16; ++kk)
        cfrag[kk] = ld_coh16(cb + (size_t)kk * 32);
    }

    // ---- init gate accumulators from prefetched G (overlaps the load wait) ----
    float4v acc0, acc1, acc2;
    #pragma unroll
    for (int r = 0; r < 4; ++r) {
      acc0[r] = bf2f(gp0[r]);
      acc1[r] = bf2f(gp1[r]);
      acc2[r] = 0.f;
    }

    asm volatile("s_waitcnt vmcnt(0)" ::: "memory");
    __builtin_amdgcn_sched_barrier(0);     // MFMAs must not hoist above the wait

    // ---- state MFMA: A and B from registers ----
    #pragma unroll
    for (int kk = 0; kk < 16; ++kk) {
      acc0 = __builtin_amdgcn_mfma_f32_16x16x32_bf16(hfrag[kk], bw0[kk], acc0, 0, 0, 0);
      acc1 = __builtin_amdgcn_mfma_f32_16x16x32_bf16(hfrag[kk], bw1[kk], acc1, 0, 0, 0);
      short8v a2 = (wid < 2) ? cfrag[kk] : hfrag[kk];
      acc2 = __builtin_amdgcn_mfma_f32_16x16x32_bf16(a2, bw2[kk], acc2, 0, 0, 0);
    }

    __syncthreads();   // barrier1: prev iteration's s_tiles readers done

    {
      const int rb = (lane >> 4) << 2, cc = lane & 15;
      #pragma unroll
      for (int r = 0; r < 4; ++r) {
        s_tiles[t0][rb + r][cc] = acc0[r];
        s_tiles[t1][rb + r][cc] = acc1[r];
        s_tiles[t2][rb + r][cc] = acc2[r];
      }
    }
    __syncthreads();   // barrier2: tiles visible

    // ---- elementwise cell update + agent-scope state store ----
    if (t < T_) {
      unsigned hpk = 0, cpk = 0;
      #pragma unroll
      for (int u = 0; u < 2; ++u) {
        int j = ejp + u;
        float iv  = s_tiles[0 + emh][ebr][j] + bI[u];
        float fv  = s_tiles[2 + emh][ebr][j] + bF[u];
        float gv  = s_tiles[4 + emh][ebr][j] + bG[u];
        float ov  = s_tiles[6 + emh][ebr][j] + bO[u];
        float c2p = s_tiles[8 + emh][ebr][j];
        float cnv = sigm(fv) * c2p + sigm(iv) * tanh_(gv);
        float hnv = sigm(ov) * tanh_(cnv);
        hpk |= ((unsigned)f2bf(hnv)) << (16 * u);
        cpk |= ((unsigned)f2bf(cnv)) << (16 * u);
      }
      size_t uso = (size_t)(t & 3) * (32 * 512) + (size_t)eb * 512 + fb * 16 + ejp;
      __hip_atomic_store((unsigned*)(HN + uso), hpk,
                         __ATOMIC_RELAXED, __HIP_MEMORY_SCOPE_AGENT);
      __hip_atomic_store((unsigned*)(CN + uso), cpk,
                         __ATOMIC_RELAXED, __HIP_MEMORY_SCOPE_AGENT);
    }
    __syncthreads();   // barrier3: vmcnt(0) drains the stores before the flag
    if (t < T_ && tid == 0)
      __hip_atomic_store(flags + fb * 16, t + 1, __ATOMIC_RELAXED, __HIP_MEMORY_SCOPE_AGENT);

    // ---- prefetch next step's G fragment (in flight across next poll) ----
    if (t + 1 < T_) {
      const ushort_t* gb = G + ((size_t)((t + 1) * 32 + fb)) * 2048 + glo;
      gp0 = *(const short4v*)(gb + gtype0 * 512);
      gp1 = *(const short4v*)(gb + gtype1 * 512);
    }

    // ---- output for step t-1 (after signaling; uses this iteration's tiles) ----
    if (t > 0) {
      float ov2[2];
      #pragma unroll
      for (int u = 0; u < 2; ++u) {
        int j = ejp + u;
        float c2p = s_tiles[8 + emh][ebr][j];
        float h2p = s_tiles[10 + emh][ebr][j];
        float att = tanh_(h2p + c2p);
        float xo  = (u ? xo2[1] : xo2[0]);
        float o1  = tanh_(att + xo);
        ov2[u] = xo + tanh_(o1);
      }
      float2v o2; o2[0] = ov2[0]; o2[1] = ov2[1];
      *(float2v*)&out[(size_t)eb * (T_ * 512) + (size_t)(t - 1) * 512 + fb * 16 + ejp] = o2;
    }
  }
}

// ===== fallback: verbatim round-4 kernel (in-loop x-pass), proven to run =====
__global__ __launch_bounds__(256, 1) void k_lstm_fb(
    const float* __restrict__ X,
    const ushort_t* __restrict__ w1, const ushort_t* __restrict__ wih,
    const ushort_t* __restrict__ wcs, const ushort_t* __restrict__ whs,
    const float* __restrict__ bias,
    ushort_t* __restrict__ HN, ushort_t* __restrict__ CN,
    int* __restrict__ flags, float* __restrict__ out)
{
  const int fb   = blockIdx.x;
  const int tid  = threadIdx.x;
  const int wid  = tid >> 6;
  const int lane = tid & 63;
  const int mh   = wid & 1;
  const int ar   = lane & 15;
  const int ko   = (lane >> 4) << 3;

  __shared__ float s_tiles[12][16][20];

  const int eb  = tid >> 3;
  const int ejp = (tid & 7) * 2;
  const int emh = eb >> 4, ebr = eb & 15;
  float bI[2], bF[2], bG[2], bO[2];
  #pragma unroll
  for (int u = 0; u < 2; ++u) {
    bI[u] = bias[0 * 512 + fb * 16 + ejp + u];
    bF[u] = bias[1 * 512 + fb * 16 + ejp + u];
    bG[u] = bias[2 * 512 + fb * 16 + ejp + u];
    bO[u] = bias[3 * 512 + fb * 16 + ejp + u];
  }

  const int gtype0 = wid >> 1;
  const int gtype1 = 2 + (wid >> 1);

  short8v bw0[16], bw1[16], bw2[16];
  {
    const ushort_t* p0 = w1 + ((size_t)(gtype0 * 512 + fb * 16 + ar)) * 512 + ko;
    const ushort_t* p1 = w1 + ((size_t)(gtype1 * 512 + fb * 16 + ar)) * 512 + ko;
    const ushort_t* p2 = ((wid < 2) ? wcs : whs) + ((size_t)(fb * 16 + ar)) * 512 + ko;
    #pragma unroll
    for (int kk = 0; kk < 16; ++kk) {
      bw0[kk] = *(const short8v*)(p0 + (size_t)kk * 32);
      bw1[kk] = *(const short8v*)(p1 + (size_t)kk * 32);
      bw2[kk] = *(const short8v*)(p2 + (size_t)kk * 32);
    }
  }

  const ushort_t* bx0_ = wih + ((size_t)(gtype0 * 512 + fb * 16 + ar)) * 512 + ko;
  const ushort_t* bx1_ = wih + ((size_t)(gtype1 * 512 + fb * 16 + ar)) * 512 + ko;
  const int arow_x = mh * 16 + ar;
  const int t0 = wid, t1 = wid + 4, t2 = wid + 8;

  for (int t = 0; t <= T_; ++t) {
    float4v acc0 = {0.f, 0.f, 0.f, 0.f};
    float4v acc1 = acc0, acc2 = acc0;

    float2v xo2 = {0.f, 0.f};
    if (t > 0)
      xo2 = *(const float2v*)&X[(size_t)eb * (T_ * 512) + (size_t)(t - 1) * 512 + fb * 16 + ejp];

    if (t < T_) {
      const float* xrow = X + (size_t)arow_x * (T_ * 512) + (size_t)t * 512 + ko;
      const ushort_t* bx0 = bx0_;
      const ushort_t* bx1 = bx1_;
      asm volatile("" : "+v"(bx0), "+v"(bx1));
      #pragma unroll
      for (int kk = 0; kk < 16; ++kk) {
        const float* p = xrow + kk * 32;
        float4v xa = *(const float4v*)(p);
        float4v xb = *(const float4v*)(p + 4);
        uint4v ua = __builtin_bit_cast(uint4v, xa);
        uint4v ub = __builtin_bit_cast(uint4v, xb);
        uint4v pk;
        pk[0] = __builtin_amdgcn_perm(ua[1], ua[0], 0x07060302u);
        pk[1] = __builtin_amdgcn_perm(ua[3], ua[2], 0x07060302u);
        pk[2] = __builtin_amdgcn_perm(ub[1], ub[0], 0x07060302u);
        pk[3] = __builtin_amdgcn_perm(ub[3], ub[2], 0x07060302u);
        short8v a = __builtin_bit_cast(short8v, pk);
        short8v b0 = *(const short8v*)(bx0 + (size_t)kk * 32);
        short8v b1 = *(const short8v*)(bx1 + (size_t)kk * 32);
        acc0 = __builtin_amdgcn_mfma_f32_16x16x32_bf16(a, b0, acc0, 0, 0, 0);
        acc1 = __builtin_amdgcn_mfma_f32_16x16x32_bf16(a, b1, acc1, 0, 0, 0);
      }
    }

    if (t > 0) {
      while (true) {
        int v = (lane < NWG)
              ? __hip_atomic_load(flags + lane * 16, __ATOMIC_RELAXED, __HIP_MEMORY_SCOPE_AGENT)
              : t;
        if (__all(v >= t)) break;
      }
      __builtin_amdgcn_sched_barrier(0);
    }

    const int rs = (t + 3) & 3;
    const ushort_t* hb = HN + (size_t)rs * (32 * 512) + (size_t)arow_x * 512 + ko;
    short8v hfrag[16];
    #pragma unroll
    for (int kk = 0; kk < 16; ++kk)
      hfrag[kk] = ld_coh16(hb + (size_t)kk * 32);
    short8v cfrag[16];
    if (wid < 2) {
      const ushort_t* cb = CN + (size_t)rs * (32 * 512) + (size_t)arow_x * 512 + ko;
      #pragma unroll
      for (int kk = 0; kk < 16; ++kk)
        cfrag[kk] = ld_coh16(cb + (size_t)kk * 32);
    }
    asm volatile("s_waitcnt vmcnt(0)" ::: "memory");
    __builtin_amdgcn_sched_barrier(0);

    #pragma unroll
    for (int kk = 0; kk < 16; ++kk) {
      acc0 = __builtin_amdgcn_mfma_f32_16x16x32_bf16(hfrag[kk], bw0[kk], acc0, 0, 0, 0);
      acc1 = __builtin_amdgcn_mfma_f32_16x16x32_bf16(hfrag[kk], bw1[kk], acc1, 0, 0, 0);
      short8v a2 = (wid < 2) ? cfrag[kk] : hfrag[kk];
      acc2 = __builtin_amdgcn_mfma_f32_16x16x32_bf16(a2, bw2[kk], acc2, 0, 0, 0);
    }

    __syncthreads();

    {
      const int rb = (lane >> 4) << 2, cc = lane & 15;
      #pragma unroll
      for (int r = 0; r < 4; ++r) {
        s_tiles[t0][rb + r][cc] = acc0[r];
        s_tiles[t1][rb + r][cc] = acc1[r];
        s_tiles[t2][rb + r][cc] = acc2[r];
      }
    }
    __syncthreads();

    if (t < T_) {
      unsigned hpk = 0, cpk = 0;
      #pragma unroll
      for (int u = 0; u < 2; ++u) {
        int j = ejp + u;
        float iv  = s_tiles[0 + emh][ebr][j] + bI[u];
        float fv  = s_tiles[2 + emh][ebr][j] + bF[u];
        float gv  = s_tiles[4 + emh][ebr][j] + bG[u];
        float ov  = s_tiles[6 + emh][ebr][j] + bO[u];
        float c2p = s_tiles[8 + emh][ebr][j];
        float cnv = sigm(fv) * c2p + sigm(iv) * tanh_(gv);
        float hnv = sigm(ov) * tanh_(cnv);
        hpk |= ((unsigned)f2bf(hnv)) << (16 * u);
        cpk |= ((unsigned)f2bf(cnv)) << (16 * u);
      }
      size_t uso = (size_t)(t & 3) * (32 * 512) + (size_t)eb * 512 + fb * 16 + ejp;
      __hip_atomic_store((unsigned*)(HN + uso), hpk,
                         __ATOMIC_RELAXED, __HIP_MEMORY_SCOPE_AGENT);
      __hip_atomic_store((unsigned*)(CN + uso), cpk,
                         __ATOMIC_RELAXED, __HIP_MEMORY_SCOPE_AGENT);
    }
    __syncthreads();
    if (t < T_ && tid == 0)
      __hip_atomic_store(flags + fb * 16, t + 1, __ATOMIC_RELAXED, __HIP_MEMORY_SCOPE_AGENT);

    if (t > 0) {
      float ov2[2];
      #pragma unroll
      for (int u = 0; u < 2; ++u) {
        int j = ejp + u;
        float c2p = s_tiles[8 + emh][ebr][j];
        float h2p = s_tiles[10 + emh][ebr][j];
        float att = tanh_(h2p + c2p);
        float xo  = (u ? xo2[1] : xo2[0]);
        float o1  = tanh_(att + xo);
        ov2[u] = xo + tanh_(o1);
      }
      float2v o2; o2[0] = ov2[0]; o2[1] = ov2[1];
      *(float2v*)&out[(size_t)eb * (T_ * 512) + (size_t)(t - 1) * 512 + fb * 16 + ejp] = o2;
    }
  }
}

extern "C" void kernel_launch(void* const* d_in, const int* in_sizes, int n_in,
                              void* d_out, int out_size, void* d_ws, size_t ws_size,
                              hipStream_t stream) {
  const float* X   = (const float*)d_in[0];
  const float* Wih = (const float*)d_in[1];
  const float* Whh = (const float*)d_in[2];
  const float* bih = (const float*)d_in[3];
  const float* bhh = (const float*)d_in[4];
  const float* Whs = (const float*)d_in[5];
  const float* Wcs = (const float*)d_in[6];

  char* ws = (char*)d_ws;
  ushort_t* w1_bf  = (ushort_t*)(ws + 0);        // 2,097,152 B
  ushort_t* wih_bf = (ushort_t*)(ws + 2097152);  // 2,097,152 B
  ushort_t* wcs_bf = (ushort_t*)(ws + 4194304);  //   524,288 B
  ushort_t* whs_bf = (ushort_t*)(ws + 4718592);  //   524,288 B
  float*    bias   = (float*)   (ws + 5242880);  //     8,192 B
  ushort_t* HN     = (ushort_t*)(ws + 5251072);  //   131,072 B (4-slot ring)
  ushort_t* CN     = (ushort_t*)(ws + 5382144);  //   131,072 B
  int*      flags  = (int*)     (ws + 5513216);  //     2,048 B (64B-padded)
  ushort_t* G      = (ushort_t*)(ws + 5515264);  // 268,435,456 B (optional)
  if (ws_size < (size_t)5515264) return;
  const bool pre = ws_size >= (size_t)5515264 + (size_t)268435456;

  k_prep_w1<<<4096, 256, 0, stream>>>(Whh, Whs, w1_bf);
  k_prep_misc<<<2048, 256, 0, stream>>>(Wih, Wcs, Whs, bih, bhh,
                                        wih_bf, wcs_bf, whs_bf, bias, HN, CN, flags);
  if (pre) {
    k_gemm_g<<<16384, 256, 0, stream>>>(X, wih_bf, G);
    k_lstm_pre<<<NWG, 256, 0, stream>>>(X, w1_bf, wcs_bf, whs_bf, bias, G,
                                        HN, CN, flags, (float*)d_out);
  } else {
    k_lstm_fb<<<NWG, 256, 0, stream>>>(X, w1_bf, wih_bf, wcs_bf, whs_bf, bias,
                                       HN, CN, flags, (float*)d_out);
  }
}

// Round 15
// 10810.206 us; speedup vs baseline: 2.0169x; 1.0585x over previous
//
#include <hip/hip_runtime.h>

#define T_   2048
#define NWG  32

typedef float  float4v __attribute__((ext_vector_type(4)));
typedef float  float2v __attribute__((ext_vector_type(2)));
typedef short  short8v __attribute__((ext_vector_type(8)));
typedef short  short4v __attribute__((ext_vector_type(4)));
typedef unsigned uint4v __attribute__((ext_vector_type(4)));
typedef unsigned short ushort_t;
typedef unsigned long long ull_t;

__device__ __forceinline__ ushort_t f2bf(float f) {
  union { float f; unsigned u; } v; v.f = f;
  unsigned r = (v.u + 0x7FFFu + ((v.u >> 16) & 1u)) >> 16;  // RTN
  return (ushort_t)r;
}
__device__ __forceinline__ float bf2f(short s) {
  union { unsigned u; float f; } v; v.u = ((unsigned)(unsigned short)s) << 16;
  return v.f;
}
__device__ __forceinline__ float sigm(float x) {
  x = fmaxf(x, -30.f);
  return __fdividef(1.f, 1.f + __expf(-x));
}
__device__ __forceinline__ float tanh_(float x) {
  x = fminf(fmaxf(x, -15.f), 15.f);
  float e = __expf(2.f * x);
  return (e - 1.f) * __fdividef(1.f, e + 1.f);
}

// Coherence-point 16B load (bypass L1+L2, no cache-wide invalidate). Plain-
// pipelined; caller must s_waitcnt vmcnt(0) before consuming.
__device__ __forceinline__ short8v ld_coh16(const ushort_t* p) {
  short8v r;
  asm volatile("global_load_dwordx4 %0, %1, off sc0 sc1" : "=v"(r) : "v"(p));
  return r;
}

// W1[n,k] = sum_j W_hh[n,j] * W_hs[j,k]   (fold: h2 @ W_hh^T == h_new @ W1^T)
__global__ void k_prep_w1(const float* __restrict__ Whh, const float* __restrict__ Whs,
                          ushort_t* __restrict__ w1) {
  int idx = blockIdx.x * 256 + threadIdx.x;
  if (idx >= 2048 * 512) return;
  int n = idx >> 9, k = idx & 511;
  const float* whr = Whh + (size_t)n * 512;
  const float* wsk = Whs + k;
  float s = 0.f;
  #pragma unroll 8
  for (int j = 0; j < 512; ++j) s += whr[j] * wsk[(size_t)j * 512];
  w1[idx] = f2bf(s);
}

__global__ void k_prep_misc(const float* __restrict__ Wih, const float* __restrict__ Wcs,
                            const float* __restrict__ Whs, const float* __restrict__ bih,
                            const float* __restrict__ bhh,
                            ushort_t* __restrict__ wih_bf, ushort_t* __restrict__ wcs_bf,
                            ushort_t* __restrict__ whs_bf, float* __restrict__ bias,
                            ushort_t* __restrict__ HN, ushort_t* __restrict__ CN,
                            int* __restrict__ flags, int* __restrict__ gcnt) {
  const int total = 1048576 + 262144 + 262144 + 2048 + 16384 + 16384 + 512 + 8192;
  for (int i = blockIdx.x * blockDim.x + threadIdx.x; i < total; i += gridDim.x * blockDim.x) {
    int r = i;
    if (r < 1048576) { wih_bf[r] = f2bf(Wih[r]); continue; }
    r -= 1048576;
    if (r < 262144)  { wcs_bf[r] = f2bf(Wcs[r]); continue; }
    r -= 262144;
    if (r < 262144)  { whs_bf[r] = f2bf(Whs[r]); continue; }
    r -= 262144;
    if (r < 2048)    { bias[r] = bih[r] + bhh[r]; continue; }
    r -= 2048;
    if (r < 16384)   { HN[3 * 16384 + r] = 0; continue; }   // zero ring slot 3 (state t=-1)
    r -= 16384;
    if (r < 16384)   { CN[3 * 16384 + r] = 0; continue; }
    r -= 16384;
    if (r < 512)     { flags[r] = 0; continue; }
    r -= 512;
    gcnt[r] = 0;   // 512 tg counters, 64B-padded
  }
}

// ===== fused kernel: 32 lstm WGs (bid<32) + 16384 gemm WGs (bid>=32) =====
// gemm role: G[t][fb][gate][col][batch] = (X_t @ Wih^T), C-fragment bf16,
//   written with AGENT-scope stores (MALL-visible), per-tg counter signal.
// lstm role: round-7 chassis verbatim; G prefetch gated by gcnt[tg] in the
//   tail slack region (free in steady state), read with agent-scope loads.
__global__ __launch_bounds__(256, 1) void k_fused(
    const float* __restrict__ X,
    const ushort_t* __restrict__ w1, const ushort_t* __restrict__ wih,
    const ushort_t* __restrict__ wcs, const ushort_t* __restrict__ whs,
    const float* __restrict__ bias, ushort_t* __restrict__ G,
    ushort_t* __restrict__ HN, ushort_t* __restrict__ CN,
    int* __restrict__ flags, int* __restrict__ gcnt, float* __restrict__ out)
{
  const int tid  = threadIdx.x;
  const int wid  = tid >> 6;
  const int lane = tid & 63;
  const int ar   = lane & 15;
  const int ko   = (lane >> 4) << 3;

  if (blockIdx.x >= 32) {
    // ---------------- gemm role ----------------
    const int gbid = blockIdx.x - 32;
    const int fb  = gbid & 31;
    const int tg  = gbid >> 5;
    const int t   = tg * 4 + wid;

    float4v acc[2][4];
    #pragma unroll
    for (int mh = 0; mh < 2; ++mh)
      #pragma unroll
      for (int cg = 0; cg < 4; ++cg)
        acc[mh][cg] = float4v{0.f, 0.f, 0.f, 0.f};

    #pragma unroll 4
    for (int kk = 0; kk < 16; ++kk) {
      short8v a[2];
      #pragma unroll
      for (int mh = 0; mh < 2; ++mh) {
        const float* p = X + (size_t)(mh * 16 + ar) * (T_ * 512) + (size_t)t * 512 + kk * 32 + ko;
        float4v xa = *(const float4v*)(p);
        float4v xb = *(const float4v*)(p + 4);
        uint4v ua = __builtin_bit_cast(uint4v, xa);
        uint4v ub = __builtin_bit_cast(uint4v, xb);
        uint4v pk;
        pk[0] = __builtin_amdgcn_perm(ua[1], ua[0], 0x07060302u);
        pk[1] = __builtin_amdgcn_perm(ua[3], ua[2], 0x07060302u);
        pk[2] = __builtin_amdgcn_perm(ub[1], ub[0], 0x07060302u);
        pk[3] = __builtin_amdgcn_perm(ub[3], ub[2], 0x07060302u);
        a[mh] = __builtin_bit_cast(short8v, pk);
      }
      #pragma unroll
      for (int cg = 0; cg < 4; ++cg) {
        short8v b = *(const short8v*)(wih + ((size_t)(cg * 512 + fb * 16 + ar)) * 512 + kk * 32 + ko);
        acc[0][cg] = __builtin_amdgcn_mfma_f32_16x16x32_bf16(a[0], b, acc[0][cg], 0, 0, 0);
        acc[1][cg] = __builtin_amdgcn_mfma_f32_16x16x32_bf16(a[1], b, acc[1][cg], 0, 0, 0);
      }
    }

    const size_t base = ((size_t)t * 32 + fb) * 2048;
    #pragma unroll
    for (int mh = 0; mh < 2; ++mh)
      #pragma unroll
      for (int cg = 0; cg < 4; ++cg) {
        short4v s;
        #pragma unroll
        for (int r = 0; r < 4; ++r) s[r] = (short)f2bf(acc[mh][cg][r]);
        __hip_atomic_store(
            (ull_t*)(G + base + cg * 512 + ar * 32 + mh * 16 + ((lane >> 4) << 2)),
            __builtin_bit_cast(ull_t, s), __ATOMIC_RELAXED, __HIP_MEMORY_SCOPE_AGENT);
      }
    __syncthreads();   // drains all threads' agent stores (vmcnt0) before signal
    if (tid == 0)
      __hip_atomic_fetch_add(gcnt + tg * 16, 1, __ATOMIC_RELAXED, __HIP_MEMORY_SCOPE_AGENT);
    return;
  }

  // ---------------- lstm role (round-7 chassis) ----------------
  const int fb = blockIdx.x;
  const int mh = wid & 1;

  __shared__ float s_tiles[12][16][20];

  const int eb  = tid >> 3;
  const int ejp = (tid & 7) * 2;
  const int emh = eb >> 4, ebr = eb & 15;
  float bI[2], bF[2], bG[2], bO[2];
  #pragma unroll
  for (int u = 0; u < 2; ++u) {
    bI[u] = bias[0 * 512 + fb * 16 + ejp + u];
    bF[u] = bias[1 * 512 + fb * 16 + ejp + u];
    bG[u] = bias[2 * 512 + fb * 16 + ejp + u];
    bO[u] = bias[3 * 512 + fb * 16 + ejp + u];
  }

  const int gtype0 = wid >> 1;
  const int gtype1 = 2 + (wid >> 1);

  // state-pass B fragments: load ONCE into registers
  short8v bw0[16], bw1[16], bw2[16];
  {
    const ushort_t* p0 = w1 + ((size_t)(gtype0 * 512 + fb * 16 + ar)) * 512 + ko;
    const ushort_t* p1 = w1 + ((size_t)(gtype1 * 512 + fb * 16 + ar)) * 512 + ko;
    const ushort_t* p2 = ((wid < 2) ? wcs : whs) + ((size_t)(fb * 16 + ar)) * 512 + ko;
    #pragma unroll
    for (int kk = 0; kk < 16; ++kk) {
      bw0[kk] = *(const short8v*)(p0 + (size_t)kk * 32);
      bw1[kk] = *(const short8v*)(p1 + (size_t)kk * 32);
      bw2[kk] = *(const short8v*)(p2 + (size_t)kk * 32);
    }
  }

  const int arow_x = mh * 16 + ar;
  const int t0 = wid, t1 = wid + 4, t2 = wid + 8;
  const int glo = ((lane >> 4) << 2) + mh * 16 + ar * 32;

  short4v gp0, gp1;
  {   // prologue: wait for gemm tg=0, then prefetch G[0] (agent loads)
    while (__hip_atomic_load(gcnt, __ATOMIC_RELAXED, __HIP_MEMORY_SCOPE_AGENT) < 32) {}
    const ushort_t* gb = G + (size_t)fb * 2048 + glo;
    gp0 = __builtin_bit_cast(short4v,
        __hip_atomic_load((const ull_t*)(gb + gtype0 * 512), __ATOMIC_RELAXED, __HIP_MEMORY_SCOPE_AGENT));
    gp1 = __builtin_bit_cast(short4v,
        __hip_atomic_load((const ull_t*)(gb + gtype1 * 512), __ATOMIC_RELAXED, __HIP_MEMORY_SCOPE_AGENT));
  }

  for (int t = 0; t <= T_; ++t) {
    // ---- prefetch output-pass X early (off the sync path) ----
    float2v xo2 = {0.f, 0.f};
    if (t > 0)
      xo2 = *(const float2v*)&X[(size_t)eb * (T_ * 512) + (size_t)(t - 1) * 512 + fb * 16 + ejp];

    // ---- poll (agent-scope relaxed atomic, padded flag slots) ----
    if (t > 0) {
      while (true) {
        int v = (lane < NWG)
              ? __hip_atomic_load(flags + lane * 16, __ATOMIC_RELAXED, __HIP_MEMORY_SCOPE_AGENT)
              : t;
        if (__all(v >= t)) break;
      }
      __builtin_amdgcn_sched_barrier(0);
    }

    // ---- state A-fragments: pipelined coherence-point loads ----
    const int rs = (t + 3) & 3;
    const ushort_t* hb = HN + (size_t)rs * (32 * 512) + (size_t)arow_x * 512 + ko;
    short8v hfrag[16];
    #pragma unroll
    for (int kk = 0; kk < 16; ++kk)
      hfrag[kk] = ld_coh16(hb + (size_t)kk * 32);
    short8v cfrag[16];
    if (wid < 2) {
      const ushort_t* cb = CN + (size_t)rs * (32 * 512) + (size_t)arow_x * 512 + ko;
      #pragma unroll
      for (int kk = 0; kk < 16; ++kk)
        cfrag[kk] = ld_coh16(cb + (size_t)kk * 32);
    }

    // ---- init gate accumulators from prefetched G (overlaps the load wait) ----
    float4v acc0, acc1, acc2;
    #pragma unroll
    for (int r = 0; r < 4; ++r) {
      acc0[r] = bf2f(gp0[r]);
      acc1[r] = bf2f(gp1[r]);
      acc2[r] = 0.f;
    }

    asm volatile("s_waitcnt vmcnt(0)" ::: "memory");
    __builtin_amdgcn_sched_barrier(0);     // MFMAs must not hoist above the wait

    // ---- state MFMA: A and B from registers ----
    #pragma unroll
    for (int kk = 0; kk < 16; ++kk) {
      acc0 = __builtin_amdgcn_mfma_f32_16x16x32_bf16(hfrag[kk], bw0[kk], acc0, 0, 0, 0);
      acc1 = __builtin_amdgcn_mfma_f32_16x16x32_bf16(hfrag[kk], bw1[kk], acc1, 0, 0, 0);
      short8v a2 = (wid < 2) ? cfrag[kk] : hfrag[kk];
      acc2 = __builtin_amdgcn_mfma_f32_16x16x32_bf16(a2, bw2[kk], acc2, 0, 0, 0);
    }

    __syncthreads();   // barrier1: prev iteration's s_tiles readers done

    {
      const int rb = (lane >> 4) << 2, cc = lane & 15;
      #pragma unroll
      for (int r = 0; r < 4; ++r) {
        s_tiles[t0][rb + r][cc] = acc0[r];
        s_tiles[t1][rb + r][cc] = acc1[r];
        s_tiles[t2][rb + r][cc] = acc2[r];
      }
    }
    __syncthreads();   // barrier2: tiles visible

    // ---- elementwise cell update + agent-scope state store ----
    if (t < T_) {
      unsigned hpk = 0, cpk = 0;
      #pragma unroll
      for (int u = 0; u < 2; ++u) {
        int j = ejp + u;
        float iv  = s_tiles[0 + emh][ebr][j] + bI[u];
        float fv  = s_tiles[2 + emh][ebr][j] + bF[u];
        float gv  = s_tiles[4 + emh][ebr][j] + bG[u];
        float ov  = s_tiles[6 + emh][ebr][j] + bO[u];
        float c2p = s_tiles[8 + emh][ebr][j];
        float cnv = sigm(fv) * c2p + sigm(iv) * tanh_(gv);
        float hnv = sigm(ov) * tanh_(cnv);
        hpk |= ((unsigned)f2bf(hnv)) << (16 * u);
        cpk |= ((unsigned)f2bf(cnv)) << (16 * u);
      }
      size_t uso = (size_t)(t & 3) * (32 * 512) + (size_t)eb * 512 + fb * 16 + ejp;
      __hip_atomic_store((unsigned*)(HN + uso), hpk,
                         __ATOMIC_RELAXED, __HIP_MEMORY_SCOPE_AGENT);
      __hip_atomic_store((unsigned*)(CN + uso), cpk,
                         __ATOMIC_RELAXED, __HIP_MEMORY_SCOPE_AGENT);
    }
    __syncthreads();   // barrier3: vmcnt(0) drains the stores before the flag
    if (t < T_ && tid == 0)
      __hip_atomic_store(flags + fb * 16, t + 1, __ATOMIC_RELAXED, __HIP_MEMORY_SCOPE_AGENT);

    // ---- prefetch next step's G fragment (tail slack region; gcnt-gated) ----
    if (t + 1 < T_) {
      if (((t + 1) & 3) == 0) {
        const int* gq = gcnt + ((t + 1) >> 2) * 16;
        while (__hip_atomic_load(gq, __ATOMIC_RELAXED, __HIP_MEMORY_SCOPE_AGENT) < 32) {}
      }
      const ushort_t* gb = G + ((size_t)((t + 1) * 32 + fb)) * 2048 + glo;
      gp0 = __builtin_bit_cast(short4v,
          __hip_atomic_load((const ull_t*)(gb + gtype0 * 512), __ATOMIC_RELAXED, __HIP_MEMORY_SCOPE_AGENT));
      gp1 = __builtin_bit_cast(short4v,
          __hip_atomic_load((const ull_t*)(gb + gtype1 * 512), __ATOMIC_RELAXED, __HIP_MEMORY_SCOPE_AGENT));
    }

    // ---- output for step t-1 (after signaling; uses this iteration's tiles) ----
    if (t > 0) {
      float ov2[2];
      #pragma unroll
      for (int u = 0; u < 2; ++u) {
        int j = ejp + u;
        float c2p = s_tiles[8 + emh][ebr][j];
        float h2p = s_tiles[10 + emh][ebr][j];
        float att = tanh_(h2p + c2p);
        float xo  = (u ? xo2[1] : xo2[0]);
        float o1  = tanh_(att + xo);
        ov2[u] = xo + tanh_(o1);
      }
      float2v o2; o2[0] = ov2[0]; o2[1] = ov2[1];
      *(float2v*)&out[(size_t)eb * (T_ * 512) + (size_t)(t - 1) * 512 + fb * 16 + ejp] = o2;
    }
  }
}

// ===== fallback: verbatim round-4 kernel (in-loop x-pass), proven to run =====
__global__ __launch_bounds__(256, 1) void k_lstm_fb(
    const float* __restrict__ X,
    const ushort_t* __restrict__ w1, const ushort_t* __restrict__ wih,
    const ushort_t* __restrict__ wcs, const ushort_t* __restrict__ whs,
    const float* __restrict__ bias,
    ushort_t* __restrict__ HN, ushort_t* __restrict__ CN,
    int* __restrict__ flags, float* __restrict__ out)
{
  const int fb   = blockIdx.x;
  const int tid  = threadIdx.x;
  const int wid  = tid >> 6;
  const int lane = tid & 63;
  const int mh   = wid & 1;
  const int ar   = lane & 15;
  const int ko   = (lane >> 4) << 3;

  __shared__ float s_tiles[12][16][20];

  const int eb  = tid >> 3;
  const int ejp = (tid & 7) * 2;
  const int emh = eb >> 4, ebr = eb & 15;
  float bI[2], bF[2], bG[2], bO[2];
  #pragma unroll
  for (int u = 0; u < 2; ++u) {
    bI[u] = bias[0 * 512 + fb * 16 + ejp + u];
    bF[u] = bias[1 * 512 + fb * 16 + ejp + u];
    bG[u] = bias[2 * 512 + fb * 16 + ejp + u];
    bO[u] = bias[3 * 512 + fb * 16 + ejp + u];
  }

  const int gtype0 = wid >> 1;
  const int gtype1 = 2 + (wid >> 1);

  short8v bw0[16], bw1[16], bw2[16];
  {
    const ushort_t* p0 = w1 + ((size_t)(gtype0 * 512 + fb * 16 + ar)) * 512 + ko;
    const ushort_t* p1 = w1 + ((size_t)(gtype1 * 512 + fb * 16 + ar)) * 512 + ko;
    const ushort_t* p2 = ((wid < 2) ? wcs : whs) + ((size_t)(fb * 16 + ar)) * 512 + ko;
    #pragma unroll
    for (int kk = 0; kk < 16; ++kk) {
      bw0[kk] = *(const short8v*)(p0 + (size_t)kk * 32);
      bw1[kk] = *(const short8v*)(p1 + (size_t)kk * 32);
      bw2[kk] = *(const short8v*)(p2 + (size_t)kk * 32);
    }
  }

  const ushort_t* bx0_ = wih + ((size_t)(gtype0 * 512 + fb * 16 + ar)) * 512 + ko;
  const ushort_t* bx1_ = wih + ((size_t)(gtype1 * 512 + fb * 16 + ar)) * 512 + ko;
  const int arow_x = mh * 16 + ar;
  const int t0 = wid, t1 = wid + 4, t2 = wid + 8;

  for (int t = 0; t <= T_; ++t) {
    float4v acc0 = {0.f, 0.f, 0.f, 0.f};
    float4v acc1 = acc0, acc2 = acc0;

    float2v xo2 = {0.f, 0.f};
    if (t > 0)
      xo2 = *(const float2v*)&X[(size_t)eb * (T_ * 512) + (size_t)(t - 1) * 512 + fb * 16 + ejp];

    if (t < T_) {
      const float* xrow = X + (size_t)arow_x * (T_ * 512) + (size_t)t * 512 + ko;
      const ushort_t* bx0 = bx0_;
      const ushort_t* bx1 = bx1_;
      asm volatile("" : "+v"(bx0), "+v"(bx1));
      #pragma unroll
      for (int kk = 0; kk < 16; ++kk) {
        const float* p = xrow + kk * 32;
        float4v xa = *(const float4v*)(p);
        float4v xb = *(const float4v*)(p + 4);
        uint4v ua = __builtin_bit_cast(uint4v, xa);
        uint4v ub = __builtin_bit_cast(uint4v, xb);
        uint4v pk;
        pk[0] = __builtin_amdgcn_perm(ua[1], ua[0], 0x07060302u);
        pk[1] = __builtin_amdgcn_perm(ua[3], ua[2], 0x07060302u);
        pk[2] = __builtin_amdgcn_perm(ub[1], ub[0], 0x07060302u);
        pk[3] = __builtin_amdgcn_perm(ub[3], ub[2], 0x07060302u);
        short8v a = __builtin_bit_cast(short8v, pk);
        short8v b0 = *(const short8v*)(bx0 + (size_t)kk * 32);
        short8v b1 = *(const short8v*)(bx1 + (size_t)kk * 32);
        acc0 = __builtin_amdgcn_mfma_f32_16x16x32_bf16(a, b0, acc0, 0, 0, 0);
        acc1 = __builtin_amdgcn_mfma_f32_16x16x32_bf16(a, b1, acc1, 0, 0, 0);
      }
    }

    if (t > 0) {
      while (true) {
        int v = (lane < NWG)
              ? __hip_atomic_load(flags + lane * 16, __ATOMIC_RELAXED, __HIP_MEMORY_SCOPE_AGENT)
              : t;
        if (__all(v >= t)) break;
      }
      __builtin_amdgcn_sched_barrier(0);
    }

    const int rs = (t + 3) & 3;
    const ushort_t* hb = HN + (size_t)rs * (32 * 512) + (size_t)arow_x * 512 + ko;
    short8v hfrag[16];
    #pragma unroll
    for (int kk = 0; kk < 16; ++kk)
      hfrag[kk] = ld_coh16(hb + (size_t)kk * 32);
    short8v cfrag[16];
    if (wid < 2) {
      const ushort_t* cb = CN + (size_t)rs * (32 * 512) + (size_t)arow_x * 512 + ko;
      #pragma unroll
      for (int kk = 0; kk < 16; ++kk)
        cfrag[kk] = ld_coh16(cb + (size_t)kk * 32);
    }
    asm volatile("s_waitcnt vmcnt(0)" ::: "memory");
    __builtin_amdgcn_sched_barrier(0);

    #pragma unroll
    for (int kk = 0; kk < 16; ++kk) {
      acc0 = __builtin_amdgcn_mfma_f32_16x16x32_bf16(hfrag[kk], bw0[kk], acc0, 0, 0, 0);
      acc1 = __builtin_amdgcn_mfma_f32_16x16x32_bf16(hfrag[kk], bw1[kk], acc1, 0, 0, 0);
      short8v a2 = (wid < 2) ? cfrag[kk] : hfrag[kk];
      acc2 = __builtin_amdgcn_mfma_f32_16x16x32_bf16(a2, bw2[kk], acc2, 0, 0, 0);
    }

    __syncthreads();

    {
      const int rb = (lane >> 4) << 2, cc = lane & 15;
      #pragma unroll
      for (int r = 0; r < 4; ++r) {
        s_tiles[t0][rb + r][cc] = acc0[r];
        s_tiles[t1][rb + r][cc] = acc1[r];
        s_tiles[t2][rb + r][cc] = acc2[r];
      }
    }
    __syncthreads();

    if (t < T_) {
      unsigned hpk = 0, cpk = 0;
      #pragma unroll
      for (int u = 0; u < 2; ++u) {
        int j = ejp + u;
        float iv  = s_tiles[0 + emh][ebr][j] + bI[u];
        float fv  = s_tiles[2 + emh][ebr][j] + bF[u];
        float gv  = s_tiles[4 + emh][ebr][j] + bG[u];
        float ov  = s_tiles[6 + emh][ebr][j] + bO[u];
        float c2p = s_tiles[8 + emh][ebr][j];
        float cnv = sigm(fv) * c2p + sigm(iv) * tanh_(gv);
        float hnv = sigm(ov) * tanh_(cnv);
        hpk |= ((unsigned)f2bf(hnv)) << (16 * u);
        cpk |= ((unsigned)f2bf(cnv)) << (16 * u);
      }
      size_t uso = (size_t)(t & 3) * (32 * 512) + (size_t)eb * 512 + fb * 16 + ejp;
      __hip_atomic_store((unsigned*)(HN + uso), hpk,
                         __ATOMIC_RELAXED, __HIP_MEMORY_SCOPE_AGENT);
      __hip_atomic_store((unsigned*)(CN + uso), cpk,
                         __ATOMIC_RELAXED, __HIP_MEMORY_SCOPE_AGENT);
    }
    __syncthreads();
    if (t < T_ && tid == 0)
      __hip_atomic_store(flags + fb * 16, t + 1, __ATOMIC_RELAXED, __HIP_MEMORY_SCOPE_AGENT);

    if (t > 0) {
      float ov2[2];
      #pragma unroll
      for (int u = 0; u < 2; ++u) {
        int j = ejp + u;
        float c2p = s_tiles[8 + emh][ebr][j];
        float h2p = s_tiles[10 + emh][ebr][j];
        float att = tanh_(h2p + c2p);
        float xo  = (u ? xo2[1] : xo2[0]);
        float o1  = tanh_(att + xo);
        ov2[u] = xo + tanh_(o1);
      }
      float2v o2; o2[0] = ov2[0]; o2[1] = ov2[1];
      *(float2v*)&out[(size_t)eb * (T_ * 512) + (size_t)(t - 1) * 512 + fb * 16 + ejp] = o2;
    }
  }
}

extern "C" void kernel_launch(void* const* d_in, const int* in_sizes, int n_in,
                              void* d_out, int out_size, void* d_ws, size_t ws_size,
                              hipStream_t stream) {
  const float* X   = (const float*)d_in[0];
  const float* Wih = (const float*)d_in[1];
  const float* Whh = (const float*)d_in[2];
  const float* bih = (const float*)d_in[3];
  const float* bhh = (const float*)d_in[4];
  const float* Whs = (const float*)d_in[5];
  const float* Wcs = (const float*)d_in[6];

  char* ws = (char*)d_ws;
  ushort_t* w1_bf  = (ushort_t*)(ws + 0);        // 2,097,152 B
  ushort_t* wih_bf = (ushort_t*)(ws + 2097152);  // 2,097,152 B
  ushort_t* wcs_bf = (ushort_t*)(ws + 4194304);  //   524,288 B
  ushort_t* whs_bf = (ushort_t*)(ws + 4718592);  //   524,288 B
  float*    bias   = (float*)   (ws + 5242880);  //     8,192 B
  ushort_t* HN     = (ushort_t*)(ws + 5251072);  //   131,072 B (4-slot ring)
  ushort_t* CN     = (ushort_t*)(ws + 5382144);  //   131,072 B
  int*      flags  = (int*)     (ws + 5513216);  //     2,048 B (64B-padded)
  int*      gcnt   = (int*)     (ws + 5515264);  //    32,768 B (512 padded tg counters)
  ushort_t* G      = (ushort_t*)(ws + 5548032);  // 268,435,456 B (optional)
  if (ws_size < (size_t)5548032) return;
  const bool pre = ws_size >= (size_t)5548032 + (size_t)268435456;

  k_prep_w1<<<4096, 256, 0, stream>>>(Whh, Whs, w1_bf);
  k_prep_misc<<<2048, 256, 0, stream>>>(Wih, Wcs, Whs, bih, bhh,
                                        wih_bf, wcs_bf, whs_bf, bias, HN, CN, flags, gcnt);
  if (pre) {
    k_fused<<<32 + 16384, 256, 0, stream>>>(X, w1_bf, wih_bf, wcs_bf, whs_bf, bias, G,
                                            HN, CN, flags, gcnt, (float*)d_out);
  } else {
    k_lstm_fb<<<NWG, 256, 0, stream>>>(X, w1_bf, wih_bf, wcs_bf, whs_bf, bias,
                                       HN, CN, flags, (float*)d_out);
  }
}